// Round 1
// baseline (11827.822 us; speedup 1.0000x reference)
//
#include <hip/hip_runtime.h>

constexpr int Cc = 512;
constexpr int Nn = 4096;   // 64*64
constexpr int Bb = 4;
#define EPS 1e-5f

// ---------------- stats: per (b,c) mean & rstd (unbiased var) ----------------
__global__ __launch_bounds__(256) void stats_kernel(const float* __restrict__ x,
                                                    float* __restrict__ mean,
                                                    float* __restrict__ rstd) {
    int bc = blockIdx.x;                     // 0 .. B*C-1
    const float* row = x + (size_t)bc * Nn;
    float s = 0.f, sq = 0.f;
    for (int i = threadIdx.x * 4; i < Nn; i += 256 * 4) {
        float4 v = *reinterpret_cast<const float4*>(row + i);
        s  += v.x + v.y + v.z + v.w;
        sq += v.x*v.x + v.y*v.y + v.z*v.z + v.w*v.w;
    }
    for (int off = 32; off; off >>= 1) {
        s  += __shfl_down(s, off);
        sq += __shfl_down(sq, off);
    }
    __shared__ float ls[4], lsq[4];
    int wid = threadIdx.x >> 6;
    if ((threadIdx.x & 63) == 0) { ls[wid] = s; lsq[wid] = sq; }
    __syncthreads();
    if (threadIdx.x == 0) {
        float S  = ls[0] + ls[1] + ls[2] + ls[3];
        float SQ = lsq[0] + lsq[1] + lsq[2] + lsq[3];
        float m  = S / (float)Nn;
        float var = (SQ - S * m) / (float)(Nn - 1);   // unbiased
        mean[bc] = m;
        rstd[bc] = rsqrtf(var + EPS);
    }
}

// ---------------- conv1x1 as per-batch GEMM: Y[o,n] = sum_c W[o,c]*Xn[c,n]+bias ----
template <bool NORM, bool RESID>
__global__ __launch_bounds__(256) void conv_gemm(const float* __restrict__ X,
                                                 const float* __restrict__ W,
                                                 const float* __restrict__ bias,
                                                 const float* __restrict__ mean,
                                                 const float* __restrict__ rstd,
                                                 const float* __restrict__ resid,
                                                 float* __restrict__ Y) {
    int b = blockIdx.z;
    const float* Xb = X + (size_t)b * Cc * Nn;
    float* Yb = Y + (size_t)b * Cc * Nn;
    int n0 = blockIdx.x * 64;
    int o0 = blockIdx.y * 64;
    __shared__ float Ws[16][64];
    __shared__ float Xs[16][64];
    int tx = threadIdx.x & 15, ty = threadIdx.x >> 4;
    float acc[4][4] = {};
    for (int k0 = 0; k0 < Cc; k0 += 16) {
        for (int i = threadIdx.x; i < 64 * 16; i += 256) {
            int o = i >> 4, kk = i & 15;
            Ws[kk][o] = W[(size_t)(o0 + o) * Cc + k0 + kk];
        }
        for (int i = threadIdx.x; i < 16 * 64; i += 256) {
            int kk = i >> 6, n = i & 63;
            float v = Xb[(size_t)(k0 + kk) * Nn + n0 + n];
            if constexpr (NORM) {
                int c = b * Cc + k0 + kk;
                v = (v - mean[c]) * rstd[c];
            }
            Xs[kk][n] = v;
        }
        __syncthreads();
#pragma unroll
        for (int kk = 0; kk < 16; ++kk) {
            const float4 a  = *reinterpret_cast<const float4*>(&Ws[kk][ty * 4]);
            const float4 bb = *reinterpret_cast<const float4*>(&Xs[kk][tx * 4]);
            float av[4] = {a.x, a.y, a.z, a.w};
            float bv[4] = {bb.x, bb.y, bb.z, bb.w};
#pragma unroll
            for (int i = 0; i < 4; ++i)
#pragma unroll
                for (int j = 0; j < 4; ++j) acc[i][j] += av[i] * bv[j];
        }
        __syncthreads();
    }
#pragma unroll
    for (int i = 0; i < 4; ++i) {
        int o = o0 + ty * 4 + i;
        float bs = bias[o];
        float4 v;
        v.x = acc[i][0] + bs; v.y = acc[i][1] + bs;
        v.z = acc[i][2] + bs; v.w = acc[i][3] + bs;
        size_t off = (size_t)o * Nn + n0 + tx * 4;
        if constexpr (RESID) {
            const float4 rr = *reinterpret_cast<const float4*>(
                &resid[(size_t)b * Cc * Nn + off]);
            v.x += rr.x; v.y += rr.y; v.z += rr.z; v.w += rr.w;
        }
        *reinterpret_cast<float4*>(&Yb[off]) = v;
    }
}

// ---------------- fused attention: O[c,q] = sum_s softmax_s(F^T G)[q,s] * H[c,s] ----
__global__ __launch_bounds__(256) void attn_kernel(const float* __restrict__ Fm,
                                                   const float* __restrict__ Gm,
                                                   const float* __restrict__ Hm,
                                                   float* __restrict__ Om) {
    constexpr int QT = 32, ST = 64, CCH = 128;
    int b = blockIdx.y;
    int q0 = blockIdx.x * QT;
    const float* Fb = Fm + (size_t)b * Cc * Nn;
    const float* Gb = Gm + (size_t)b * Cc * Nn;
    const float* Hb = Hm + (size_t)b * Cc * Nn;
    float* Ob = Om + (size_t)b * Cc * Nn;

    __shared__ float Fs[CCH][QT];      // 16 KB
    __shared__ float Gs[CCH][ST];      // 32 KB (G tiles, then H tiles)
    __shared__ float P[QT][68];        // logits / probs (stride 68: 16B-aligned rows)
    __shared__ float mrow[QT], lrow[QT], srow[QT], psum[QT][8];

    int t = threadIdx.x;
    int q = t & 31, grp = t >> 5;      // grp 0..7

    float Oacc[64];
#pragma unroll
    for (int i = 0; i < 64; ++i) Oacc[i] = 0.f;
    if (t < QT) { mrow[t] = -1e30f; lrow[t] = 0.f; }

    for (int s0 = 0; s0 < Nn; s0 += ST) {
        float acc[8] = {};
        // -------- logits: S[q, s0+s] = sum_c F[c,q0+q] * G[c,s0+s] --------
        for (int c0 = 0; c0 < Cc; c0 += CCH) {
            __syncthreads();
            for (int i = t; i < CCH * QT; i += 256) {
                int c = i >> 5, qq = i & 31;
                Fs[c][qq] = Fb[(size_t)(c0 + c) * Nn + q0 + qq];
            }
            for (int i = t; i < CCH * ST; i += 256) {
                int c = i >> 6, ss = i & 63;
                Gs[c][ss] = Gb[(size_t)(c0 + c) * Nn + s0 + ss];
            }
            __syncthreads();
#pragma unroll 8
            for (int c = 0; c < CCH; ++c) {
                float f = Fs[c][q];
                const float4 g0 = *reinterpret_cast<const float4*>(&Gs[c][grp * 8]);
                const float4 g1 = *reinterpret_cast<const float4*>(&Gs[c][grp * 8 + 4]);
                acc[0] += f * g0.x; acc[1] += f * g0.y;
                acc[2] += f * g0.z; acc[3] += f * g0.w;
                acc[4] += f * g1.x; acc[5] += f * g1.y;
                acc[6] += f * g1.z; acc[7] += f * g1.w;
            }
        }
#pragma unroll
        for (int i = 0; i < 8; ++i) P[q][grp * 8 + i] = acc[i];
        __syncthreads();
        // -------- online softmax --------
        if (t < QT) {
            float mt = -1e30f;
            for (int s = 0; s < ST; ++s) mt = fmaxf(mt, P[t][s]);
            float mn = fmaxf(mrow[t], mt);
            srow[t] = __expf(mrow[t] - mn);
            mrow[t] = mn;
        }
        __syncthreads();
        float mq = mrow[q];
        float part = 0.f;
#pragma unroll
        for (int i = 0; i < 8; ++i) {
            float p = __expf(P[q][grp * 8 + i] - mq);
            P[q][grp * 8 + i] = p;
            part += p;
        }
        psum[q][grp] = part;
        __syncthreads();
        if (t < QT) {
            float s = 0.f;
#pragma unroll
            for (int i = 0; i < 8; ++i) s += psum[t][i];
            lrow[t] = lrow[t] * srow[t] + s;
        }
        float sc = srow[q];
#pragma unroll
        for (int i = 0; i < 64; ++i) Oacc[i] *= sc;
        // -------- PV: O[q,c] += sum_s P[q,s] * H[c,s] --------
        for (int c0 = 0; c0 < Cc; c0 += CCH) {
            __syncthreads();
            for (int i = t; i < CCH * ST; i += 256) {
                int c = i >> 6, ss = i & 63;
                Gs[c][ss] = Hb[(size_t)(c0 + c) * Nn + s0 + ss];
            }
            __syncthreads();
            int segbase = (c0 >> 7) * 4;
#pragma unroll
            for (int s4 = 0; s4 < 16; ++s4) {
                const float4 p = *reinterpret_cast<const float4*>(&P[q][s4 * 4]);
#pragma unroll
                for (int sl = 0; sl < 4; ++sl) {
                    int cl = sl * 32 + grp * 4;
#pragma unroll
                    for (int r = 0; r < 4; ++r) {
                        const float4 h =
                            *reinterpret_cast<const float4*>(&Gs[cl + r][s4 * 4]);
                        Oacc[(segbase + sl) * 4 + r] +=
                            p.x * h.x + p.y * h.y + p.z * h.z + p.w * h.w;
                    }
                }
            }
        }
    }
    __syncthreads();
    // -------- normalize by l and store via LDS staging (coalesced) --------
    float linv = 1.f / lrow[q];
    for (int rd = 0; rd < 4; ++rd) {
#pragma unroll
        for (int sl = 0; sl < 4; ++sl) {
            int seg = rd * 4 + sl;
            int lc = sl * 32 + grp * 4;
#pragma unroll
            for (int r = 0; r < 4; ++r)
                Fs[lc + r][q] = Oacc[seg * 4 + r] * linv;
        }
        __syncthreads();
        for (int i = t; i < CCH * QT; i += 256) {
            int c = i >> 5, qq = i & 31;
            Ob[(size_t)(rd * CCH + c) * Nn + q0 + qq] = Fs[c][qq];
        }
        __syncthreads();
    }
}

extern "C" void kernel_launch(void* const* d_in, const int* in_sizes, int n_in,
                              void* d_out, int out_size, void* d_ws, size_t ws_size,
                              hipStream_t stream) {
    const float* content = (const float*)d_in[0];
    const float* style   = (const float*)d_in[1];
    const float* f_w = (const float*)d_in[2];
    const float* f_b = (const float*)d_in[3];
    const float* g_w = (const float*)d_in[4];
    const float* g_b = (const float*)d_in[5];
    const float* h_w = (const float*)d_in[6];
    const float* h_b = (const float*)d_in[7];
    const float* o_w = (const float*)d_in[8];
    const float* o_b = (const float*)d_in[9];
    float* out = (float*)d_out;
    float* ws  = (float*)d_ws;

    const size_t TEN = (size_t)Bb * Cc * Nn;   // 8M floats
    float* Fm = ws;
    float* Gm = ws + TEN;
    float* Hm = ws + 2 * TEN;
    float* Om = ws + 3 * TEN;
    float* meanC = ws + 4 * TEN;
    float* rstdC = meanC + Bb * Cc;
    float* meanS = rstdC + Bb * Cc;
    float* rstdS = meanS + Bb * Cc;

    stats_kernel<<<Bb * Cc, 256, 0, stream>>>(content, meanC, rstdC);
    stats_kernel<<<Bb * Cc, 256, 0, stream>>>(style, meanS, rstdS);

    dim3 cgrid(Nn / 64, Cc / 64, Bb);
    conv_gemm<true, false><<<cgrid, 256, 0, stream>>>(content, f_w, f_b, meanC, rstdC, nullptr, Fm);
    conv_gemm<true, false><<<cgrid, 256, 0, stream>>>(style, g_w, g_b, meanS, rstdS, nullptr, Gm);
    conv_gemm<false, false><<<cgrid, 256, 0, stream>>>(style, h_w, h_b, nullptr, nullptr, nullptr, Hm);

    attn_kernel<<<dim3(Nn / 32, Bb), 256, 0, stream>>>(Fm, Gm, Hm, Om);

    conv_gemm<false, true><<<cgrid, 256, 0, stream>>>(Om, o_w, o_b, nullptr, nullptr, content, out);
}

// Round 2
// 1444.030 us; speedup vs baseline: 8.1908x; 8.1908x over previous
//
#include <hip/hip_runtime.h>

constexpr int Cc = 512;
constexpr int Nn = 4096;   // 64*64
constexpr int Bb = 4;
#define EPS 1e-5f

using bf16x8 = __attribute__((ext_vector_type(8))) short;
using f32x4  = __attribute__((ext_vector_type(4))) float;

__device__ __forceinline__ unsigned short f2bf(float f) {
    union { float f; unsigned int u; } v; v.f = f;
    unsigned int r = v.u + 0x7fffu + ((v.u >> 16) & 1u);   // RNE
    return (unsigned short)(r >> 16);
}
__device__ __forceinline__ float bf2f(unsigned short h) {
    union { unsigned int u; float f; } v; v.u = ((unsigned int)h) << 16;
    return v.f;
}
__device__ __forceinline__ void gload_lds16(const void* g, void* l) {
    __builtin_amdgcn_global_load_lds(
        (const __attribute__((address_space(1))) void*)g,
        (__attribute__((address_space(3))) void*)l, 16, 0, 0);
}

// ---------------- stats: per (b,c) mean & rstd (unbiased var) ----------------
__global__ __launch_bounds__(256) void stats_kernel(const float* __restrict__ x,
                                                    float* __restrict__ mean,
                                                    float* __restrict__ rstd) {
    int bc = blockIdx.x;
    const float* row = x + (size_t)bc * Nn;
    float s = 0.f, sq = 0.f;
    for (int i = threadIdx.x * 4; i < Nn; i += 256 * 4) {
        float4 v = *reinterpret_cast<const float4*>(row + i);
        s  += v.x + v.y + v.z + v.w;
        sq += v.x*v.x + v.y*v.y + v.z*v.z + v.w*v.w;
    }
    for (int off = 32; off; off >>= 1) {
        s  += __shfl_down(s, off);
        sq += __shfl_down(sq, off);
    }
    __shared__ float ls[4], lsq[4];
    int wid = threadIdx.x >> 6;
    if ((threadIdx.x & 63) == 0) { ls[wid] = s; lsq[wid] = sq; }
    __syncthreads();
    if (threadIdx.x == 0) {
        float S  = ls[0] + ls[1] + ls[2] + ls[3];
        float SQ = lsq[0] + lsq[1] + lsq[2] + lsq[3];
        float m  = S / (float)Nn;
        float var = (SQ - S * m) / (float)(Nn - 1);
        mean[bc] = m;
        rstd[bc] = rsqrtf(var + EPS);
    }
}

// ---------------- conv1x1 as per-batch fp32 GEMM ----------------
template <bool NORM, bool RESID>
__global__ __launch_bounds__(256) void conv_gemm(const float* __restrict__ X,
                                                 const float* __restrict__ W,
                                                 const float* __restrict__ bias,
                                                 const float* __restrict__ mean,
                                                 const float* __restrict__ rstd,
                                                 const float* __restrict__ resid,
                                                 float* __restrict__ Y) {
    int b = blockIdx.z;
    const float* Xb = X + (size_t)b * Cc * Nn;
    float* Yb = Y + (size_t)b * Cc * Nn;
    int n0 = blockIdx.x * 64;
    int o0 = blockIdx.y * 64;
    __shared__ float Ws[16][64];
    __shared__ float Xs[16][64];
    int tx = threadIdx.x & 15, ty = threadIdx.x >> 4;
    float acc[4][4] = {};
    for (int k0 = 0; k0 < Cc; k0 += 16) {
        for (int i = threadIdx.x; i < 64 * 16; i += 256) {
            int o = i >> 4, kk = i & 15;
            Ws[kk][o] = W[(size_t)(o0 + o) * Cc + k0 + kk];
        }
        for (int i = threadIdx.x; i < 16 * 64; i += 256) {
            int kk = i >> 6, n = i & 63;
            float v = Xb[(size_t)(k0 + kk) * Nn + n0 + n];
            if constexpr (NORM) {
                int c = b * Cc + k0 + kk;
                v = (v - mean[c]) * rstd[c];
            }
            Xs[kk][n] = v;
        }
        __syncthreads();
#pragma unroll
        for (int kk = 0; kk < 16; ++kk) {
            const float4 a  = *reinterpret_cast<const float4*>(&Ws[kk][ty * 4]);
            const float4 bb = *reinterpret_cast<const float4*>(&Xs[kk][tx * 4]);
            float av[4] = {a.x, a.y, a.z, a.w};
            float bv[4] = {bb.x, bb.y, bb.z, bb.w};
#pragma unroll
            for (int i = 0; i < 4; ++i)
#pragma unroll
                for (int j = 0; j < 4; ++j) acc[i][j] += av[i] * bv[j];
        }
        __syncthreads();
    }
#pragma unroll
    for (int i = 0; i < 4; ++i) {
        int o = o0 + ty * 4 + i;
        float bs = bias[o];
        float4 v;
        v.x = acc[i][0] + bs; v.y = acc[i][1] + bs;
        v.z = acc[i][2] + bs; v.w = acc[i][3] + bs;
        size_t off = (size_t)o * Nn + n0 + tx * 4;
        if constexpr (RESID) {
            const float4 rr = *reinterpret_cast<const float4*>(
                &resid[(size_t)b * Cc * Nn + off]);
            v.x += rr.x; v.y += rr.y; v.z += rr.z; v.w += rr.w;
        }
        *reinterpret_cast<float4*>(&Yb[off]) = v;
    }
}

// ------------- pack fp32 [b][c][n] -> bf16 hi/lo transposed [b][n][c] -------------
__global__ __launch_bounds__(256) void pack_split_T(const float* __restrict__ X,
                                                    unsigned short* __restrict__ Thi,
                                                    unsigned short* __restrict__ Tlo) {
    int b = blockIdx.z;
    int n0 = blockIdx.x * 64, c0 = blockIdx.y * 64;
    __shared__ float tile[64][65];
    const float* Xb = X + (size_t)b * Cc * Nn;
    for (int i = threadIdx.x; i < 64 * 64; i += 256) {
        int c = i >> 6, n = i & 63;
        tile[c][n] = Xb[(size_t)(c0 + c) * Nn + n0 + n];
    }
    __syncthreads();
    unsigned short* Hb = Thi + (size_t)b * Nn * Cc;
    unsigned short* Lb = Tlo + (size_t)b * Nn * Cc;
    for (int i = threadIdx.x; i < 64 * 64; i += 256) {
        int n = i >> 6, c = i & 63;
        float x = tile[c][n];
        unsigned short hi = f2bf(x);
        unsigned short lo = f2bf(x - bf2f(hi));
        Hb[(size_t)(n0 + n) * Cc + c0 + c] = hi;
        Lb[(size_t)(n0 + n) * Cc + c0 + c] = lo;
    }
}

// ------------- elementwise fp32 -> bf16 (keeps layout) -------------
__global__ __launch_bounds__(256) void pack_bf16(const float* __restrict__ X,
                                                 unsigned short* __restrict__ Y,
                                                 int ntotal4) {
    int i = blockIdx.x * 256 + threadIdx.x;
    if (i >= ntotal4) return;
    float4 v = reinterpret_cast<const float4*>(X)[i];
    unsigned long long pk = (unsigned long long)f2bf(v.x)
        | ((unsigned long long)f2bf(v.y) << 16)
        | ((unsigned long long)f2bf(v.z) << 32)
        | ((unsigned long long)f2bf(v.w) << 48);
    reinterpret_cast<unsigned long long*>(Y)[i] = pk;
}

// ------------- MFMA GEMM: C[m][n] = sum_k A[m][k]*B[k][n] -------------
// A stored m-major: Ahi[(m)*lda + k]; B stored n-major: Bhi[(n)*ldb + k].
// 128x128 tile, BK=32, 4 waves (2x2), each wave 64x64 = 4x4 frags of 16x16x32.
// SPLIT: A,B each have hi/lo bf16 planes; acc = Ahi*Bhi + Ahi*Blo + Alo*Bhi.
template <bool SPLIT>
__global__ __launch_bounds__(256) void mfma_gemm_tn(
    const unsigned short* __restrict__ Ahi, const unsigned short* __restrict__ Alo,
    int lda, long long strideA,
    const unsigned short* __restrict__ Bhi, const unsigned short* __restrict__ Blo,
    int ldb, long long strideB,
    float* __restrict__ C, int ldc, long long strideC, int K) {
    __shared__ unsigned short smem[SPLIT ? 16384 : 8192];
    unsigned short* As_hi = smem;              // 128x32
    unsigned short* Bs_hi = smem + 4096;       // 128x32
    unsigned short* As_lo = nullptr;
    unsigned short* Bs_lo = nullptr;
    if constexpr (SPLIT) { As_lo = smem + 8192; Bs_lo = smem + 12288; }

    int bz = blockIdx.z;
    const unsigned short* Ah = Ahi + (size_t)bz * strideA;
    const unsigned short* Bh = Bhi + (size_t)bz * strideB;
    const unsigned short* Al = nullptr;
    const unsigned short* Bl = nullptr;
    if constexpr (SPLIT) { Al = Alo + (size_t)bz * strideA; Bl = Blo + (size_t)bz * strideB; }
    float* Cb = C + (size_t)bz * strideC;

    int m0 = blockIdx.y * 128, n0 = blockIdx.x * 128;
    int tid = threadIdx.x, wave = tid >> 6, lane = tid & 63;
    int wr = wave >> 1, wc = wave & 1;
    int lr = lane & 15, lg = lane >> 4;

    f32x4 acc[4][4];
#pragma unroll
    for (int i = 0; i < 4; ++i)
#pragma unroll
        for (int j = 0; j < 4; ++j) acc[i][j] = (f32x4){0.f, 0.f, 0.f, 0.f};

    for (int k0 = 0; k0 < K; k0 += 32) {
        __syncthreads();    // previous compute done before overwrite
        // stage tiles: each tile 128x32 bf16 = 8KB = 8 chunks of 1KB; wave handles 2 chunks
#pragma unroll
        for (int i = 0; i < 2; ++i) {
            int chunk = wave * 2 + i;
            int e0 = chunk * 512 + lane * 8;
            int rr = e0 >> 5, cc = e0 & 31;
            gload_lds16(Ah + (size_t)(m0 + rr) * lda + k0 + cc, As_hi + chunk * 512);
            gload_lds16(Bh + (size_t)(n0 + rr) * ldb + k0 + cc, Bs_hi + chunk * 512);
            if constexpr (SPLIT) {
                gload_lds16(Al + (size_t)(m0 + rr) * lda + k0 + cc, As_lo + chunk * 512);
                gload_lds16(Bl + (size_t)(n0 + rr) * ldb + k0 + cc, Bs_lo + chunk * 512);
            }
        }
        asm volatile("s_waitcnt vmcnt(0)" ::: "memory");
        __syncthreads();

        bf16x8 ah[4], bh[4];
#pragma unroll
        for (int x = 0; x < 4; ++x) {
            ah[x] = *reinterpret_cast<const bf16x8*>(&As_hi[(wr * 64 + x * 16 + lr) * 32 + lg * 8]);
            bh[x] = *reinterpret_cast<const bf16x8*>(&Bs_hi[(wc * 64 + x * 16 + lr) * 32 + lg * 8]);
        }
        if constexpr (SPLIT) {
            bf16x8 al[4], bl[4];
#pragma unroll
            for (int x = 0; x < 4; ++x) {
                al[x] = *reinterpret_cast<const bf16x8*>(&As_lo[(wr * 64 + x * 16 + lr) * 32 + lg * 8]);
                bl[x] = *reinterpret_cast<const bf16x8*>(&Bs_lo[(wc * 64 + x * 16 + lr) * 32 + lg * 8]);
            }
#pragma unroll
            for (int mi = 0; mi < 4; ++mi)
#pragma unroll
                for (int ni = 0; ni < 4; ++ni) {
                    acc[mi][ni] = __builtin_amdgcn_mfma_f32_16x16x32_bf16(ah[mi], bh[ni], acc[mi][ni], 0, 0, 0);
                    acc[mi][ni] = __builtin_amdgcn_mfma_f32_16x16x32_bf16(ah[mi], bl[ni], acc[mi][ni], 0, 0, 0);
                    acc[mi][ni] = __builtin_amdgcn_mfma_f32_16x16x32_bf16(al[mi], bh[ni], acc[mi][ni], 0, 0, 0);
                }
        } else {
#pragma unroll
            for (int mi = 0; mi < 4; ++mi)
#pragma unroll
                for (int ni = 0; ni < 4; ++ni)
                    acc[mi][ni] = __builtin_amdgcn_mfma_f32_16x16x32_bf16(ah[mi], bh[ni], acc[mi][ni], 0, 0, 0);
        }
    }
    // epilogue: D row = lg*4 + r, col = lr  (within each 16x16 frag)
#pragma unroll
    for (int mi = 0; mi < 4; ++mi) {
        int row = m0 + wr * 64 + mi * 16 + lg * 4;
#pragma unroll
        for (int ni = 0; ni < 4; ++ni) {
            int col = n0 + wc * 64 + ni * 16 + lr;
#pragma unroll
            for (int r = 0; r < 4; ++r)
                Cb[(size_t)(row + r) * ldc + col] = acc[mi][ni][r];
        }
    }
}

// ------------- row softmax fp32 -> normalized P bf16 -------------
__global__ __launch_bounds__(256) void softmax_kernel(const float* __restrict__ S,
                                                      unsigned short* __restrict__ P) {
    int row = blockIdx.x;
    const float4* r4 = reinterpret_cast<const float4*>(S + (size_t)row * Nn);
    int t = threadIdx.x;
    float4 v[4];
    float mx = -1e30f;
#pragma unroll
    for (int j = 0; j < 4; ++j) {
        v[j] = r4[t + 256 * j];
        mx = fmaxf(mx, fmaxf(fmaxf(v[j].x, v[j].y), fmaxf(v[j].z, v[j].w)));
    }
    for (int off = 32; off; off >>= 1) mx = fmaxf(mx, __shfl_down(mx, off));
    __shared__ float redm[4], reds[4];
    int wid = t >> 6;
    if ((t & 63) == 0) redm[wid] = mx;
    __syncthreads();
    mx = fmaxf(fmaxf(redm[0], redm[1]), fmaxf(redm[2], redm[3]));
    float s = 0.f;
#pragma unroll
    for (int j = 0; j < 4; ++j) {
        v[j].x = __expf(v[j].x - mx); v[j].y = __expf(v[j].y - mx);
        v[j].z = __expf(v[j].z - mx); v[j].w = __expf(v[j].w - mx);
        s += v[j].x + v[j].y + v[j].z + v[j].w;
    }
    for (int off = 32; off; off >>= 1) s += __shfl_down(s, off);
    if ((t & 63) == 0) reds[wid] = s;
    __syncthreads();
    s = reds[0] + reds[1] + reds[2] + reds[3];
    float inv = 1.f / s;
    unsigned long long* P8 = reinterpret_cast<unsigned long long*>(P + (size_t)row * Nn);
#pragma unroll
    for (int j = 0; j < 4; ++j) {
        unsigned long long pk = (unsigned long long)f2bf(v[j].x * inv)
            | ((unsigned long long)f2bf(v[j].y * inv) << 16)
            | ((unsigned long long)f2bf(v[j].z * inv) << 32)
            | ((unsigned long long)f2bf(v[j].w * inv) << 48);
        P8[t + 256 * j] = pk;
    }
}

extern "C" void kernel_launch(void* const* d_in, const int* in_sizes, int n_in,
                              void* d_out, int out_size, void* d_ws, size_t ws_size,
                              hipStream_t stream) {
    const float* content = (const float*)d_in[0];
    const float* style   = (const float*)d_in[1];
    const float* f_w = (const float*)d_in[2];
    const float* f_b = (const float*)d_in[3];
    const float* g_w = (const float*)d_in[4];
    const float* g_b = (const float*)d_in[5];
    const float* h_w = (const float*)d_in[6];
    const float* h_b = (const float*)d_in[7];
    const float* o_w = (const float*)d_in[8];
    const float* o_b = (const float*)d_in[9];
    float* out = (float*)d_out;
    char* ws = (char*)d_ws;

    const size_t TEN = (size_t)Bb * Cc * Nn;           // 8,388,608 elems
    const size_t SZ_F32 = TEN * 4;                     // 32 MiB
    const size_t SMAT = (size_t)Nn * Nn;               // 16,777,216 elems

    float* Ffp = (float*)(ws);
    float* Gfp = (float*)(ws + SZ_F32);
    float* Hfp = (float*)(ws + 2 * SZ_F32);
    float* S_buf = (float*)(ws);                       // 64MB overlay of F+G (dead after pack)
    float* O_fp  = (float*)(ws + 2 * SZ_F32);          // overlay of H (dead after pack)
    unsigned short* FThi = (unsigned short*)(ws + 3 * SZ_F32);
    unsigned short* FTlo = FThi + TEN;
    unsigned short* GThi = FTlo + TEN;
    unsigned short* GTlo = GThi + TEN;
    unsigned short* Hbf  = GTlo + TEN;
    float* meanC = (float*)(Hbf + TEN);
    float* rstdC = meanC + Bb * Cc;
    float* meanS = rstdC + Bb * Cc;
    float* rstdS = meanS + Bb * Cc;
    unsigned short* P = (unsigned short*)(rstdS + Bb * Cc);
    size_t base_used = (size_t)((char*)P - ws);
    bool pv_batched = ws_size >= base_used + (size_t)Bb * SMAT * 2;

    stats_kernel<<<Bb * Cc, 256, 0, stream>>>(content, meanC, rstdC);
    stats_kernel<<<Bb * Cc, 256, 0, stream>>>(style, meanS, rstdS);

    dim3 cgrid(Nn / 64, Cc / 64, Bb);
    conv_gemm<true, false><<<cgrid, 256, 0, stream>>>(content, f_w, f_b, meanC, rstdC, nullptr, Ffp);
    conv_gemm<true, false><<<cgrid, 256, 0, stream>>>(style, g_w, g_b, meanS, rstdS, nullptr, Gfp);
    conv_gemm<false, false><<<cgrid, 256, 0, stream>>>(style, h_w, h_b, nullptr, nullptr, nullptr, Hfp);

    dim3 pgrid(Nn / 64, Cc / 64, Bb);
    pack_split_T<<<pgrid, 256, 0, stream>>>(Ffp, FThi, FTlo);
    pack_split_T<<<pgrid, 256, 0, stream>>>(Gfp, GThi, GTlo);
    pack_bf16<<<(int)(TEN / 4 + 255) / 256, 256, 0, stream>>>(Hfp, Hbf, (int)(TEN / 4));

    for (int b = 0; b < Bb; ++b) {
        const size_t tb = (size_t)b * Nn * Cc;
        // S[q][s] = sum_c F_T[q][c] * G_T[s][c]   (M=N=4096, K=512), split 3-pass
        mfma_gemm_tn<true><<<dim3(Nn / 128, Nn / 128, 1), 256, 0, stream>>>(
            FThi + tb, FTlo + tb, Cc, 0,
            GThi + tb, GTlo + tb, Cc, 0,
            S_buf, Nn, 0, Cc);
        softmax_kernel<<<Nn, 256, 0, stream>>>(S_buf, P + (pv_batched ? (size_t)b * SMAT : 0));
        if (!pv_batched) {
            // O[c][q] = sum_s Hbf[c][s] * P[q][s]   (M=512, N=4096, K=4096)
            mfma_gemm_tn<false><<<dim3(Nn / 128, Cc / 128, 1), 256, 0, stream>>>(
                Hbf + (size_t)b * Cc * Nn, nullptr, Nn, 0,
                P, nullptr, Nn, 0,
                O_fp + (size_t)b * Cc * Nn, Nn, 0, Nn);
        }
    }
    if (pv_batched) {
        mfma_gemm_tn<false><<<dim3(Nn / 128, Cc / 128, Bb), 256, 0, stream>>>(
            Hbf, nullptr, Nn, (long long)Cc * Nn,
            P, nullptr, Nn, (long long)SMAT,
            O_fp, Nn, (long long)Cc * Nn, Nn);
    }

    conv_gemm<false, true><<<cgrid, 256, 0, stream>>>(O_fp, o_w, o_b, nullptr, nullptr, content, out);
}

// Round 3
// 869.398 us; speedup vs baseline: 13.6046x; 1.6610x over previous
//
#include <hip/hip_runtime.h>

constexpr int Cc = 512;
constexpr int Nn = 4096;   // 64*64
constexpr int Bb = 4;
#define EPS 1e-5f

using bf16x8 = __attribute__((ext_vector_type(8))) short;
using f32x4  = __attribute__((ext_vector_type(4))) float;
typedef unsigned short us;

__device__ __forceinline__ us f2bf(float f) {
    union { float f; unsigned int u; } v; v.f = f;
    unsigned int r = v.u + 0x7fffu + ((v.u >> 16) & 1u);   // RNE
    return (us)(r >> 16);
}
__device__ __forceinline__ float bf2f(us h) {
    union { unsigned int u; float f; } v; v.u = ((unsigned int)h) << 16;
    return v.f;
}
__device__ __forceinline__ void gload_lds16(const void* g, void* l) {
    __builtin_amdgcn_global_load_lds(
        (const __attribute__((address_space(1))) void*)g,
        (__attribute__((address_space(3))) void*)l, 16, 0, 0);
}

// ---------------- stats: per (b,c) mean & rstd (unbiased var) ----------------
__global__ __launch_bounds__(256) void stats_kernel(const float* __restrict__ x,
                                                    float* __restrict__ mean,
                                                    float* __restrict__ rstd) {
    int bc = blockIdx.x;
    const float* row = x + (size_t)bc * Nn;
    float s = 0.f, sq = 0.f;
    for (int i = threadIdx.x * 4; i < Nn; i += 256 * 4) {
        float4 v = *reinterpret_cast<const float4*>(row + i);
        s  += v.x + v.y + v.z + v.w;
        sq += v.x*v.x + v.y*v.y + v.z*v.z + v.w*v.w;
    }
    for (int off = 32; off; off >>= 1) {
        s  += __shfl_down(s, off);
        sq += __shfl_down(sq, off);
    }
    __shared__ float ls[4], lsq[4];
    int wid = threadIdx.x >> 6;
    if ((threadIdx.x & 63) == 0) { ls[wid] = s; lsq[wid] = sq; }
    __syncthreads();
    if (threadIdx.x == 0) {
        float S  = ls[0] + ls[1] + ls[2] + ls[3];
        float SQ = lsq[0] + lsq[1] + lsq[2] + lsq[3];
        float m  = S / (float)Nn;
        float var = (SQ - S * m) / (float)(Nn - 1);
        mean[bc] = m;
        rstd[bc] = rsqrtf(var + EPS);
    }
}

// ------ pack fp32 [b][c][n] -> bf16 (hi[,lo]) transposed [b][n][c], fused norm ------
template <bool NORM, bool SPLIT>
__global__ __launch_bounds__(256) void pack_T(const float* __restrict__ X,
                                              const float* __restrict__ mean,
                                              const float* __restrict__ rstd,
                                              us* __restrict__ Thi,
                                              us* __restrict__ Tlo) {
    int b = blockIdx.z;
    int n0 = blockIdx.x * 64, c0 = blockIdx.y * 64;
    __shared__ float tile[64][65];
    const float* Xb = X + (size_t)b * Cc * Nn;
    for (int i = threadIdx.x; i < 64 * 64; i += 256) {
        int c = i >> 6, n = i & 63;
        float v = Xb[(size_t)(c0 + c) * Nn + n0 + n];
        if constexpr (NORM) {
            int cg = b * Cc + c0 + c;
            v = (v - mean[cg]) * rstd[cg];
        }
        tile[c][n] = v;
    }
    __syncthreads();
    us* Hb = Thi + (size_t)b * Nn * Cc;
    for (int i = threadIdx.x; i < 64 * 64; i += 256) {
        int n = i >> 6, c = i & 63;
        float x = tile[c][n];
        us hi = f2bf(x);
        Hb[(size_t)(n0 + n) * Cc + c0 + c] = hi;
        if constexpr (SPLIT) {
            us lo = f2bf(x - bf2f(hi));
            (Tlo + (size_t)b * Nn * Cc)[(size_t)(n0 + n) * Cc + c0 + c] = lo;
        }
    }
}

// ------ pack the four 512x512 weights: f,g split hi/lo; h,o plain bf16 ------
__global__ __launch_bounds__(256) void pack_w(const float* __restrict__ fw, const float* __restrict__ gw,
                                              const float* __restrict__ hw, const float* __restrict__ ow,
                                              us* __restrict__ fh, us* __restrict__ fl,
                                              us* __restrict__ gh, us* __restrict__ gl,
                                              us* __restrict__ hb, us* __restrict__ ob) {
    int i = blockIdx.x * 256 + threadIdx.x;
    if (i >= Cc * Cc) return;
    float v = fw[i]; us hi = f2bf(v); fh[i] = hi; fl[i] = f2bf(v - bf2f(hi));
    v = gw[i]; hi = f2bf(v); gh[i] = hi; gl[i] = f2bf(v - bf2f(hi));
    hb[i] = f2bf(hw[i]);
    ob[i] = f2bf(ow[i]);
}

// ------------- MFMA GEMM: C[m][n'] = sum_k A[m][k]*B[n'][k] -------------
// A m-major (lda elems/row), B n'-major (ldb elems/row). 128x128 tile, BK=32,
// 4 waves (2x2), each wave 64x64 = 4x4 frags of mfma_f32_16x16x32_bf16.
// SPLIT: A,B have hi/lo planes; acc = Ah*Bh + Ah*Bl + Al*Bh (Ootomo split).
// EPI: 0 = fp32 store, 1 = bf16 store, 2 = split hi/lo store.
// BIAS: 0 none, 1 bias[row], 2 bias[col].  RESID: add resid[row*ldc+col].
template <bool SPLIT, int EPI, int BIAS, bool RESID>
__global__ __launch_bounds__(256) void mfma_gemm(
    const us* __restrict__ Ahi, const us* __restrict__ Alo, int lda, long long strideA,
    const us* __restrict__ Bhi, const us* __restrict__ Blo, int ldb, long long strideB,
    void* __restrict__ out0, void* __restrict__ out1, int ldc, long long strideC,
    const float* __restrict__ bias, const float* __restrict__ resid, long long strideR,
    int K) {
    __shared__ us smem[SPLIT ? 16384 : 8192];
    us* As_hi = smem;                    // 128x32
    us* Bs_hi = smem + 4096;             // 128x32
    us* As_lo = nullptr;
    us* Bs_lo = nullptr;
    if constexpr (SPLIT) { As_lo = smem + 8192; Bs_lo = smem + 12288; }

    int bz = blockIdx.z;
    const us* Ah = Ahi + (size_t)bz * strideA;
    const us* Bh = Bhi + (size_t)bz * strideB;
    const us* Al = nullptr;
    const us* Bl = nullptr;
    if constexpr (SPLIT) { Al = Alo + (size_t)bz * strideA; Bl = Blo + (size_t)bz * strideB; }

    int m0 = blockIdx.y * 128, n0 = blockIdx.x * 128;
    int tid = threadIdx.x, wave = tid >> 6, lane = tid & 63;
    int wr = wave >> 1, wc = wave & 1;
    int lr = lane & 15, lg = lane >> 4;

    f32x4 acc[4][4];
#pragma unroll
    for (int i = 0; i < 4; ++i)
#pragma unroll
        for (int j = 0; j < 4; ++j) acc[i][j] = (f32x4){0.f, 0.f, 0.f, 0.f};

    for (int k0 = 0; k0 < K; k0 += 32) {
        __syncthreads();
#pragma unroll
        for (int i = 0; i < 2; ++i) {
            int chunk = wave * 2 + i;
            int e0 = chunk * 512 + lane * 8;
            int rr = e0 >> 5, cc = e0 & 31;
            gload_lds16(Ah + (size_t)(m0 + rr) * lda + k0 + cc, As_hi + chunk * 512);
            gload_lds16(Bh + (size_t)(n0 + rr) * ldb + k0 + cc, Bs_hi + chunk * 512);
            if constexpr (SPLIT) {
                gload_lds16(Al + (size_t)(m0 + rr) * lda + k0 + cc, As_lo + chunk * 512);
                gload_lds16(Bl + (size_t)(n0 + rr) * ldb + k0 + cc, Bs_lo + chunk * 512);
            }
        }
        asm volatile("s_waitcnt vmcnt(0)" ::: "memory");
        __syncthreads();

        bf16x8 ah[4], bh[4];
#pragma unroll
        for (int x = 0; x < 4; ++x) {
            ah[x] = *reinterpret_cast<const bf16x8*>(&As_hi[(wr * 64 + x * 16 + lr) * 32 + lg * 8]);
            bh[x] = *reinterpret_cast<const bf16x8*>(&Bs_hi[(wc * 64 + x * 16 + lr) * 32 + lg * 8]);
        }
        if constexpr (SPLIT) {
            bf16x8 al[4], bl[4];
#pragma unroll
            for (int x = 0; x < 4; ++x) {
                al[x] = *reinterpret_cast<const bf16x8*>(&As_lo[(wr * 64 + x * 16 + lr) * 32 + lg * 8]);
                bl[x] = *reinterpret_cast<const bf16x8*>(&Bs_lo[(wc * 64 + x * 16 + lr) * 32 + lg * 8]);
            }
#pragma unroll
            for (int mi = 0; mi < 4; ++mi)
#pragma unroll
                for (int ni = 0; ni < 4; ++ni) {
                    acc[mi][ni] = __builtin_amdgcn_mfma_f32_16x16x32_bf16(ah[mi], bh[ni], acc[mi][ni], 0, 0, 0);
                    acc[mi][ni] = __builtin_amdgcn_mfma_f32_16x16x32_bf16(ah[mi], bl[ni], acc[mi][ni], 0, 0, 0);
                    acc[mi][ni] = __builtin_amdgcn_mfma_f32_16x16x32_bf16(al[mi], bh[ni], acc[mi][ni], 0, 0, 0);
                }
        } else {
#pragma unroll
            for (int mi = 0; mi < 4; ++mi)
#pragma unroll
                for (int ni = 0; ni < 4; ++ni)
                    acc[mi][ni] = __builtin_amdgcn_mfma_f32_16x16x32_bf16(ah[mi], bh[ni], acc[mi][ni], 0, 0, 0);
        }
    }
    // epilogue: frag D element (lg*4+r, lr)
#pragma unroll
    for (int mi = 0; mi < 4; ++mi) {
        int row = m0 + wr * 64 + mi * 16 + lg * 4;
#pragma unroll
        for (int ni = 0; ni < 4; ++ni) {
            int col = n0 + wc * 64 + ni * 16 + lr;
#pragma unroll
            for (int r = 0; r < 4; ++r) {
                float v = acc[mi][ni][r];
                if constexpr (BIAS == 1) v += bias[row + r];
                if constexpr (BIAS == 2) v += bias[col];
                if constexpr (RESID)
                    v += resid[(size_t)bz * strideR + (size_t)(row + r) * ldc + col];
                size_t off = (size_t)bz * strideC + (size_t)(row + r) * ldc + col;
                if constexpr (EPI == 0) {
                    ((float*)out0)[off] = v;
                } else if constexpr (EPI == 1) {
                    ((us*)out0)[off] = f2bf(v);
                } else {
                    us hi = f2bf(v);
                    ((us*)out0)[off] = hi;
                    ((us*)out1)[off] = f2bf(v - bf2f(hi));
                }
            }
        }
    }
}

// ------------- row softmax fp32 -> normalized P bf16 -------------
__global__ __launch_bounds__(256) void softmax_kernel(const float* __restrict__ S,
                                                      us* __restrict__ P) {
    int row = blockIdx.x;
    const float4* r4 = reinterpret_cast<const float4*>(S + (size_t)row * Nn);
    int t = threadIdx.x;
    float4 v[4];
    float mx = -1e30f;
#pragma unroll
    for (int j = 0; j < 4; ++j) {
        v[j] = r4[t + 256 * j];
        mx = fmaxf(mx, fmaxf(fmaxf(v[j].x, v[j].y), fmaxf(v[j].z, v[j].w)));
    }
    for (int off = 32; off; off >>= 1) mx = fmaxf(mx, __shfl_down(mx, off));
    __shared__ float redm[4], reds[4];
    int wid = t >> 6;
    if ((t & 63) == 0) redm[wid] = mx;
    __syncthreads();
    mx = fmaxf(fmaxf(redm[0], redm[1]), fmaxf(redm[2], redm[3]));
    float s = 0.f;
#pragma unroll
    for (int j = 0; j < 4; ++j) {
        v[j].x = __expf(v[j].x - mx); v[j].y = __expf(v[j].y - mx);
        v[j].z = __expf(v[j].z - mx); v[j].w = __expf(v[j].w - mx);
        s += v[j].x + v[j].y + v[j].z + v[j].w;
    }
    for (int off = 32; off; off >>= 1) s += __shfl_down(s, off);
    if ((t & 63) == 0) reds[wid] = s;
    __syncthreads();
    s = reds[0] + reds[1] + reds[2] + reds[3];
    float inv = 1.f / s;
    unsigned long long* P8 = reinterpret_cast<unsigned long long*>(P + (size_t)row * Nn);
#pragma unroll
    for (int j = 0; j < 4; ++j) {
        unsigned long long pk = (unsigned long long)f2bf(v[j].x * inv)
            | ((unsigned long long)f2bf(v[j].y * inv) << 16)
            | ((unsigned long long)f2bf(v[j].z * inv) << 32)
            | ((unsigned long long)f2bf(v[j].w * inv) << 48);
        P8[t + 256 * j] = pk;
    }
}

extern "C" void kernel_launch(void* const* d_in, const int* in_sizes, int n_in,
                              void* d_out, int out_size, void* d_ws, size_t ws_size,
                              hipStream_t stream) {
    const float* content = (const float*)d_in[0];
    const float* style   = (const float*)d_in[1];
    const float* f_w = (const float*)d_in[2];
    const float* f_b = (const float*)d_in[3];
    const float* g_w = (const float*)d_in[4];
    const float* g_b = (const float*)d_in[5];
    const float* h_w = (const float*)d_in[6];
    const float* h_b = (const float*)d_in[7];
    const float* o_w = (const float*)d_in[8];
    const float* o_b = (const float*)d_in[9];
    float* out = (float*)d_out;
    char* ws = (char*)d_ws;

    const size_t PB  = (size_t)Cc * Nn;        // 2,097,152 elems per batch-plane
    const size_t TEN = PB * Bb;                // 8,388,608 elems (16 MB as bf16)
    const size_t SMAT = (size_t)Nn * Nn;       // 16,777,216

    // region A [0,80MB): packed inputs; reused as S fp32 [0,64MB) after convs
    us* CNhi = (us*)ws;
    us* CNlo = CNhi + TEN;
    us* SNhi = CNlo + TEN;
    us* SNlo = SNhi + TEN;
    us* SR   = SNlo + TEN;
    float* S_buf = (float*)ws;                 // 64MB overlay (CN+SN dead by then)
    // region B [80,176MB): conv outputs
    us* FThi = SR + TEN;
    us* FTlo = FThi + TEN;
    us* GThi = FTlo + TEN;
    us* GTlo = GThi + TEN;
    us* Hbf  = GTlo + TEN;
    us* OT   = Hbf + TEN;
    // region C: packed weights + stats
    us* fwh = OT + TEN;
    us* fwl = fwh + Cc * Cc;
    us* gwh = fwl + Cc * Cc;
    us* gwl = gwh + Cc * Cc;
    us* hwb = gwl + Cc * Cc;
    us* owb = hwb + Cc * Cc;
    float* meanC = (float*)(owb + Cc * Cc);
    float* rstdC = meanC + Bb * Cc;
    float* meanS = rstdC + Bb * Cc;
    float* rstdS = meanS + Bb * Cc;
    us* P = (us*)(rstdS + Bb * Cc);
    size_t base_used = (size_t)((char*)P - ws);
    bool pv_batched = ws_size >= base_used + (size_t)Bb * SMAT * 2;

    stats_kernel<<<Bb * Cc, 256, 0, stream>>>(content, meanC, rstdC);
    stats_kernel<<<Bb * Cc, 256, 0, stream>>>(style, meanS, rstdS);

    dim3 pgrid(Nn / 64, Cc / 64, Bb);
    pack_T<true, true><<<pgrid, 256, 0, stream>>>(content, meanC, rstdC, CNhi, CNlo);
    pack_T<true, true><<<pgrid, 256, 0, stream>>>(style, meanS, rstdS, SNhi, SNlo);
    pack_T<false, false><<<pgrid, 256, 0, stream>>>(style, nullptr, nullptr, SR, nullptr);
    pack_w<<<(Cc * Cc + 255) / 256, 256, 0, stream>>>(f_w, g_w, h_w, o_w,
                                                      fwh, fwl, gwh, gwl, hwb, owb);

    // F^T[q][c'] = sum_c CN[q][c] f_w[c'][c] + f_b[c']   (M=4096, N=512, K=512)
    mfma_gemm<true, 2, 2, false><<<dim3(4, 32, Bb), 256, 0, stream>>>(
        CNhi, CNlo, Cc, (long long)PB, fwh, fwl, Cc, 0,
        FThi, FTlo, Cc, (long long)PB, f_b, nullptr, 0, Cc);
    // G^T likewise
    mfma_gemm<true, 2, 2, false><<<dim3(4, 32, Bb), 256, 0, stream>>>(
        SNhi, SNlo, Cc, (long long)PB, gwh, gwl, Cc, 0,
        GThi, GTlo, Cc, (long long)PB, g_b, nullptr, 0, Cc);
    // H[c'][s] = sum_c h_w[c'][c] SR[s][c] + h_b[c']    (M=512, N=4096, K=512)
    mfma_gemm<false, 1, 1, false><<<dim3(32, 4, Bb), 256, 0, stream>>>(
        hwb, nullptr, Cc, 0, SR, nullptr, Cc, (long long)PB,
        Hbf, nullptr, Nn, (long long)PB, h_b, nullptr, 0, Cc);

    for (int b = 0; b < Bb; ++b) {
        const size_t tb = (size_t)b * PB;
        // S[q][s] = sum_c F^T[q][c] G^T[s][c]   (M=N=4096, K=512), split 3-pass
        mfma_gemm<true, 0, 0, false><<<dim3(32, 32, 1), 256, 0, stream>>>(
            FThi + tb, FTlo + tb, Cc, 0, GThi + tb, GTlo + tb, Cc, 0,
            S_buf, nullptr, Nn, 0, nullptr, nullptr, 0, Cc);
        softmax_kernel<<<Nn, 256, 0, stream>>>(S_buf, P + (pv_batched ? (size_t)b * SMAT : 0));
        if (!pv_batched) {
            // O^T[q][c'] = sum_s P[q][s] H[c'][s]   (M=4096, N=512, K=4096)
            mfma_gemm<false, 1, 0, false><<<dim3(4, 32, 1), 256, 0, stream>>>(
                P, nullptr, Nn, 0, Hbf + tb, nullptr, Nn, 0,
                OT + tb, nullptr, Cc, 0, nullptr, nullptr, 0, Nn);
        }
    }
    if (pv_batched) {
        mfma_gemm<false, 1, 0, false><<<dim3(4, 32, Bb), 256, 0, stream>>>(
            P, nullptr, Nn, (long long)SMAT, Hbf, nullptr, Nn, (long long)PB,
            OT, nullptr, Cc, (long long)PB, nullptr, nullptr, 0, Nn);
    }

    // out[c'][n] = sum_c o_w[c'][c] O^T[n][c] + o_b[c'] + content[c'][n]
    mfma_gemm<false, 0, 1, true><<<dim3(32, 4, Bb), 256, 0, stream>>>(
        owb, nullptr, Cc, 0, OT, nullptr, Cc, (long long)PB,
        out, nullptr, Nn, (long long)PB, o_b, content, (long long)PB, Cc);
}

// Round 4
// 717.343 us; speedup vs baseline: 16.4884x; 1.2120x over previous
//
#include <hip/hip_runtime.h>

constexpr int Cc = 512;
constexpr int Nn = 4096;   // 64*64
constexpr int Bb = 4;
#define EPS 1e-5f

using bf16x8 = __attribute__((ext_vector_type(8))) short;
using f32x4  = __attribute__((ext_vector_type(4))) float;
typedef unsigned short us;

__device__ __forceinline__ us f2bf(float f) {
    union { float f; unsigned int u; } v; v.f = f;
    unsigned int r = v.u + 0x7fffu + ((v.u >> 16) & 1u);   // RNE
    return (us)(r >> 16);
}
__device__ __forceinline__ float bf2f(us h) {
    union { unsigned int u; float f; } v; v.u = ((unsigned int)h) << 16;
    return v.f;
}
__device__ __forceinline__ void gload_lds16(const void* g, void* l) {
    __builtin_amdgcn_global_load_lds(
        (const __attribute__((address_space(1))) void*)g,
        (__attribute__((address_space(3))) void*)l, 16, 0, 0);
}

// ---------------- stats: per (b,c) mean & rstd (unbiased var) ----------------
__global__ __launch_bounds__(256) void stats_kernel(const float* __restrict__ x,
                                                    float* __restrict__ mean,
                                                    float* __restrict__ rstd) {
    int bc = blockIdx.x;
    const float* row = x + (size_t)bc * Nn;
    float s = 0.f, sq = 0.f;
    for (int i = threadIdx.x * 4; i < Nn; i += 256 * 4) {
        float4 v = *reinterpret_cast<const float4*>(row + i);
        s  += v.x + v.y + v.z + v.w;
        sq += v.x*v.x + v.y*v.y + v.z*v.z + v.w*v.w;
    }
    for (int off = 32; off; off >>= 1) {
        s  += __shfl_down(s, off);
        sq += __shfl_down(sq, off);
    }
    __shared__ float ls[4], lsq[4];
    int wid = threadIdx.x >> 6;
    if ((threadIdx.x & 63) == 0) { ls[wid] = s; lsq[wid] = sq; }
    __syncthreads();
    if (threadIdx.x == 0) {
        float S  = ls[0] + ls[1] + ls[2] + ls[3];
        float SQ = lsq[0] + lsq[1] + lsq[2] + lsq[3];
        float m  = S / (float)Nn;
        float var = (SQ - S * m) / (float)(Nn - 1);
        mean[bc] = m;
        rstd[bc] = rsqrtf(var + EPS);
    }
}

// ------ pack fp32 [b][c][n] -> bf16 (hi[,lo]) transposed [b][n][c], fused norm ------
template <bool NORM, bool SPLIT>
__global__ __launch_bounds__(256) void pack_T(const float* __restrict__ X,
                                              const float* __restrict__ mean,
                                              const float* __restrict__ rstd,
                                              us* __restrict__ Thi,
                                              us* __restrict__ Tlo) {
    int b = blockIdx.z;
    int n0 = blockIdx.x * 64, c0 = blockIdx.y * 64;
    __shared__ float tile[64][65];
    const float* Xb = X + (size_t)b * Cc * Nn;
    for (int i = threadIdx.x; i < 64 * 64; i += 256) {
        int c = i >> 6, n = i & 63;
        float v = Xb[(size_t)(c0 + c) * Nn + n0 + n];
        if constexpr (NORM) {
            int cg = b * Cc + c0 + c;
            v = (v - mean[cg]) * rstd[cg];
        }
        tile[c][n] = v;
    }
    __syncthreads();
    us* Hb = Thi + (size_t)b * Nn * Cc;
    for (int i = threadIdx.x; i < 64 * 64; i += 256) {
        int n = i >> 6, c = i & 63;
        float x = tile[c][n];
        us hi = f2bf(x);
        Hb[(size_t)(n0 + n) * Cc + c0 + c] = hi;
        if constexpr (SPLIT) {
            us lo = f2bf(x - bf2f(hi));
            (Tlo + (size_t)b * Nn * Cc)[(size_t)(n0 + n) * Cc + c0 + c] = lo;
        }
    }
}

// ------ pack the four 512x512 weights: f,g split hi/lo; h,o plain bf16 ------
__global__ __launch_bounds__(256) void pack_w(const float* __restrict__ fw, const float* __restrict__ gw,
                                              const float* __restrict__ hw, const float* __restrict__ ow,
                                              us* __restrict__ fh, us* __restrict__ fl,
                                              us* __restrict__ gh, us* __restrict__ gl,
                                              us* __restrict__ hb, us* __restrict__ ob) {
    int i = blockIdx.x * 256 + threadIdx.x;
    if (i >= Cc * Cc) return;
    float v = fw[i]; us hi = f2bf(v); fh[i] = hi; fl[i] = f2bf(v - bf2f(hi));
    v = gw[i]; hi = f2bf(v); gh[i] = hi; gl[i] = f2bf(v - bf2f(hi));
    hb[i] = f2bf(hw[i]);
    ob[i] = f2bf(ow[i]);
}

// ------------- MFMA GEMM: C[m][n'] = sum_k A[m][k]*B[n'][k] -------------
// A m-major (lda), B n'-major (ldb). BMxBN tile, BK=32, 4 waves (2x2),
// wave tile (BM/2)x(BN/2) in 16x16x32 frags.
// SPLIT: hi/lo planes, acc = Ah*Bh + Ah*Bl + Al*Bh (Ootomo split).
// EPI: 0 fp32, 1 bf16, 2 split hi/lo.  BIAS: 0 none, 1 bias[row], 2 bias[col].
template <bool SPLIT, int EPI, int BIAS, bool RESID, int BM, int BN>
__global__ __launch_bounds__(256) void mfma_gemm(
    const us* __restrict__ Ahi, const us* __restrict__ Alo, int lda, long long strideA,
    const us* __restrict__ Bhi, const us* __restrict__ Blo, int ldb, long long strideB,
    void* __restrict__ out0, void* __restrict__ out1, int ldc, long long strideC,
    const float* __restrict__ bias, const float* __restrict__ resid, long long strideR,
    int K) {
    constexpr int WM = BM / 2, WN = BN / 2;
    constexpr int MI = WM / 16, NI = WN / 16;
    constexpr int AE = BM * 32, BE = BN * 32;   // elems per tile
    __shared__ us smem[SPLIT ? 2 * (AE + BE) : (AE + BE)];
    us* As_hi = smem;
    us* Bs_hi = smem + AE;
    us* As_lo = nullptr;
    us* Bs_lo = nullptr;
    if constexpr (SPLIT) { As_lo = smem + AE + BE; Bs_lo = As_lo + AE; }

    int bz = blockIdx.z;
    const us* Ah = Ahi + (size_t)bz * strideA;
    const us* Bh = Bhi + (size_t)bz * strideB;
    const us* Al = nullptr;
    const us* Bl = nullptr;
    if constexpr (SPLIT) { Al = Alo + (size_t)bz * strideA; Bl = Blo + (size_t)bz * strideB; }

    int m0 = blockIdx.y * BM, n0 = blockIdx.x * BN;
    int tid = threadIdx.x, wave = tid >> 6, lane = tid & 63;
    int wr = wave >> 1, wc = wave & 1;
    int lr = lane & 15, lg = lane >> 4;

    f32x4 acc[MI][NI];
#pragma unroll
    for (int i = 0; i < MI; ++i)
#pragma unroll
        for (int j = 0; j < NI; ++j) acc[i][j] = (f32x4){0.f, 0.f, 0.f, 0.f};

    for (int k0 = 0; k0 < K; k0 += 32) {
        __syncthreads();
        // stage: 1KB chunks (512 elems, 16 rows of 32), distributed over waves
#pragma unroll
        for (int ch = wave; ch < BM / 16; ch += 4) {
            int e0 = ch * 512 + lane * 8;
            int rr = e0 >> 5, cc = e0 & 31;
            gload_lds16(Ah + (size_t)(m0 + rr) * lda + k0 + cc, As_hi + ch * 512);
            if constexpr (SPLIT)
                gload_lds16(Al + (size_t)(m0 + rr) * lda + k0 + cc, As_lo + ch * 512);
        }
#pragma unroll
        for (int ch = wave; ch < BN / 16; ch += 4) {
            int e0 = ch * 512 + lane * 8;
            int rr = e0 >> 5, cc = e0 & 31;
            gload_lds16(Bh + (size_t)(n0 + rr) * ldb + k0 + cc, Bs_hi + ch * 512);
            if constexpr (SPLIT)
                gload_lds16(Bl + (size_t)(n0 + rr) * ldb + k0 + cc, Bs_lo + ch * 512);
        }
        asm volatile("s_waitcnt vmcnt(0)" ::: "memory");
        __syncthreads();

        bf16x8 ah[MI], bh[NI];
#pragma unroll
        for (int x = 0; x < MI; ++x)
            ah[x] = *reinterpret_cast<const bf16x8*>(&As_hi[(wr * WM + x * 16 + lr) * 32 + lg * 8]);
#pragma unroll
        for (int x = 0; x < NI; ++x)
            bh[x] = *reinterpret_cast<const bf16x8*>(&Bs_hi[(wc * WN + x * 16 + lr) * 32 + lg * 8]);
        if constexpr (SPLIT) {
            bf16x8 al[MI], bl[NI];
#pragma unroll
            for (int x = 0; x < MI; ++x)
                al[x] = *reinterpret_cast<const bf16x8*>(&As_lo[(wr * WM + x * 16 + lr) * 32 + lg * 8]);
#pragma unroll
            for (int x = 0; x < NI; ++x)
                bl[x] = *reinterpret_cast<const bf16x8*>(&Bs_lo[(wc * WN + x * 16 + lr) * 32 + lg * 8]);
#pragma unroll
            for (int mi = 0; mi < MI; ++mi)
#pragma unroll
                for (int ni = 0; ni < NI; ++ni) {
                    acc[mi][ni] = __builtin_amdgcn_mfma_f32_16x16x32_bf16(ah[mi], bh[ni], acc[mi][ni], 0, 0, 0);
                    acc[mi][ni] = __builtin_amdgcn_mfma_f32_16x16x32_bf16(ah[mi], bl[ni], acc[mi][ni], 0, 0, 0);
                    acc[mi][ni] = __builtin_amdgcn_mfma_f32_16x16x32_bf16(al[mi], bh[ni], acc[mi][ni], 0, 0, 0);
                }
        } else {
#pragma unroll
            for (int mi = 0; mi < MI; ++mi)
#pragma unroll
                for (int ni = 0; ni < NI; ++ni)
                    acc[mi][ni] = __builtin_amdgcn_mfma_f32_16x16x32_bf16(ah[mi], bh[ni], acc[mi][ni], 0, 0, 0);
        }
    }
    // epilogue: frag D element (lg*4+r, lr)
#pragma unroll
    for (int mi = 0; mi < MI; ++mi) {
        int row = m0 + wr * WM + mi * 16 + lg * 4;
#pragma unroll
        for (int ni = 0; ni < NI; ++ni) {
            int col = n0 + wc * WN + ni * 16 + lr;
#pragma unroll
            for (int r = 0; r < 4; ++r) {
                float v = acc[mi][ni][r];
                if constexpr (BIAS == 1) v += bias[row + r];
                if constexpr (BIAS == 2) v += bias[col];
                if constexpr (RESID)
                    v += resid[(size_t)bz * strideR + (size_t)(row + r) * ldc + col];
                size_t off = (size_t)bz * strideC + (size_t)(row + r) * ldc + col;
                if constexpr (EPI == 0) {
                    ((float*)out0)[off] = v;
                } else if constexpr (EPI == 1) {
                    ((us*)out0)[off] = f2bf(v);
                } else {
                    us hi = f2bf(v);
                    ((us*)out0)[off] = hi;
                    ((us*)out1)[off] = f2bf(v - bf2f(hi));
                }
            }
        }
    }
}

// ------------- row softmax fp32 -> normalized P bf16 -------------
__global__ __launch_bounds__(256) void softmax_kernel(const float* __restrict__ S,
                                                      us* __restrict__ P) {
    int row = blockIdx.x;
    const float4* r4 = reinterpret_cast<const float4*>(S + (size_t)row * Nn);
    int t = threadIdx.x;
    float4 v[4];
    float mx = -1e30f;
#pragma unroll
    for (int j = 0; j < 4; ++j) {
        v[j] = r4[t + 256 * j];
        mx = fmaxf(mx, fmaxf(fmaxf(v[j].x, v[j].y), fmaxf(v[j].z, v[j].w)));
    }
    for (int off = 32; off; off >>= 1) mx = fmaxf(mx, __shfl_down(mx, off));
    __shared__ float redm[4], reds[4];
    int wid = t >> 6;
    if ((t & 63) == 0) redm[wid] = mx;
    __syncthreads();
    mx = fmaxf(fmaxf(redm[0], redm[1]), fmaxf(redm[2], redm[3]));
    float s = 0.f;
#pragma unroll
    for (int j = 0; j < 4; ++j) {
        v[j].x = __expf(v[j].x - mx); v[j].y = __expf(v[j].y - mx);
        v[j].z = __expf(v[j].z - mx); v[j].w = __expf(v[j].w - mx);
        s += v[j].x + v[j].y + v[j].z + v[j].w;
    }
    for (int off = 32; off; off >>= 1) s += __shfl_down(s, off);
    if ((t & 63) == 0) reds[wid] = s;
    __syncthreads();
    s = reds[0] + reds[1] + reds[2] + reds[3];
    float inv = 1.f / s;
    unsigned long long* P8 = reinterpret_cast<unsigned long long*>(P + (size_t)row * Nn);
#pragma unroll
    for (int j = 0; j < 4; ++j) {
        unsigned long long pk = (unsigned long long)f2bf(v[j].x * inv)
            | ((unsigned long long)f2bf(v[j].y * inv) << 16)
            | ((unsigned long long)f2bf(v[j].z * inv) << 32)
            | ((unsigned long long)f2bf(v[j].w * inv) << 48);
        P8[t + 256 * j] = pk;
    }
}

extern "C" void kernel_launch(void* const* d_in, const int* in_sizes, int n_in,
                              void* d_out, int out_size, void* d_ws, size_t ws_size,
                              hipStream_t stream) {
    const float* content = (const float*)d_in[0];
    const float* style   = (const float*)d_in[1];
    const float* f_w = (const float*)d_in[2];
    const float* f_b = (const float*)d_in[3];
    const float* g_w = (const float*)d_in[4];
    const float* g_b = (const float*)d_in[5];
    const float* h_w = (const float*)d_in[6];
    const float* h_b = (const float*)d_in[7];
    const float* o_w = (const float*)d_in[8];
    const float* o_b = (const float*)d_in[9];
    float* out = (float*)d_out;
    char* ws = (char*)d_ws;

    const size_t PB  = (size_t)Cc * Nn;        // 2,097,152 elems per batch-plane
    const size_t TEN = PB * Bb;                // 8,388,608 elems (16 MB as bf16)
    const size_t SMAT = (size_t)Nn * Nn;       // 16,777,216

    // region A [0,80MB): packed inputs; reused as S fp32 [0,64MB) after convs
    us* CNhi = (us*)ws;
    us* CNlo = CNhi + TEN;
    us* SNhi = CNlo + TEN;
    us* SNlo = SNhi + TEN;
    us* SR   = SNlo + TEN;
    float* S_buf = (float*)ws;                 // 64MB overlay (CN+SN dead by then)
    // region B [80,176MB): conv outputs
    us* FThi = SR + TEN;
    us* FTlo = FThi + TEN;
    us* GThi = FTlo + TEN;
    us* GTlo = GThi + TEN;
    us* Hbf  = GTlo + TEN;
    us* OT   = Hbf + TEN;
    // region C: packed weights + stats + P (per-batch, 32MB)
    us* fwh = OT + TEN;
    us* fwl = fwh + Cc * Cc;
    us* gwh = fwl + Cc * Cc;
    us* gwl = gwh + Cc * Cc;
    us* hwb = gwl + Cc * Cc;
    us* owb = hwb + Cc * Cc;
    float* meanC = (float*)(owb + Cc * Cc);
    float* rstdC = meanC + Bb * Cc;
    float* meanS = rstdC + Bb * Cc;
    float* rstdS = meanS + Bb * Cc;
    us* P = (us*)(rstdS + Bb * Cc);

    stats_kernel<<<Bb * Cc, 256, 0, stream>>>(content, meanC, rstdC);
    stats_kernel<<<Bb * Cc, 256, 0, stream>>>(style, meanS, rstdS);

    dim3 pgrid(Nn / 64, Cc / 64, Bb);
    pack_T<true, true><<<pgrid, 256, 0, stream>>>(content, meanC, rstdC, CNhi, CNlo);
    pack_T<true, true><<<pgrid, 256, 0, stream>>>(style, meanS, rstdS, SNhi, SNlo);
    pack_T<false, false><<<pgrid, 256, 0, stream>>>(style, nullptr, nullptr, SR, nullptr);
    pack_w<<<(Cc * Cc + 255) / 256, 256, 0, stream>>>(f_w, g_w, h_w, o_w,
                                                      fwh, fwl, gwh, gwl, hwb, owb);

    // F^T[q][c'] = sum_c CN[q][c] f_w[c'][c] + f_b[c']   (M=4096, N=512, K=512)
    mfma_gemm<true, 2, 2, false, 128, 128><<<dim3(4, 32, Bb), 256, 0, stream>>>(
        CNhi, CNlo, Cc, (long long)PB, fwh, fwl, Cc, 0,
        FThi, FTlo, Cc, (long long)PB, f_b, nullptr, 0, Cc);
    // G^T likewise
    mfma_gemm<true, 2, 2, false, 128, 128><<<dim3(4, 32, Bb), 256, 0, stream>>>(
        SNhi, SNlo, Cc, (long long)PB, gwh, gwl, Cc, 0,
        GThi, GTlo, Cc, (long long)PB, g_b, nullptr, 0, Cc);
    // H[c'][s] = sum_c h_w[c'][c] SR[s][c] + h_b[c']    (M=512, N=4096, K=512)
    mfma_gemm<false, 1, 1, false, 128, 128><<<dim3(32, 4, Bb), 256, 0, stream>>>(
        hwb, nullptr, Cc, 0, SR, nullptr, Cc, (long long)PB,
        Hbf, nullptr, Nn, (long long)PB, h_b, nullptr, 0, Cc);

    for (int b = 0; b < Bb; ++b) {
        const size_t tb = (size_t)b * PB;
        // S[q][s] = sum_c F^T[q][c] G^T[s][c]   (M=N=4096, K=512), split 3-pass
        mfma_gemm<true, 0, 0, false, 128, 128><<<dim3(32, 32, 1), 256, 0, stream>>>(
            FThi + tb, FTlo + tb, Cc, 0, GThi + tb, GTlo + tb, Cc, 0,
            S_buf, nullptr, Nn, 0, nullptr, nullptr, 0, Cc);
        softmax_kernel<<<Nn, 256, 0, stream>>>(S_buf, P);
        // O^T[q][c'] = sum_s P[q][s] H[c'][s]   (M=4096, N=512, K=4096), 64x64 tiles
        mfma_gemm<false, 1, 0, false, 64, 64><<<dim3(Cc / 64, Nn / 64, 1), 256, 0, stream>>>(
            P, nullptr, Nn, 0, Hbf + tb, nullptr, Nn, 0,
            OT + tb, nullptr, Cc, 0, nullptr, nullptr, 0, Nn);
    }

    // out[c'][n] = sum_c o_w[c'][c] O^T[n][c] + o_b[c'] + content[c'][n]
    mfma_gemm<false, 0, 1, true, 128, 128><<<dim3(32, 4, Bb), 256, 0, stream>>>(
        owb, nullptr, Cc, 0, OT, nullptr, Cc, (long long)PB,
        out, nullptr, Nn, (long long)PB, o_b, content, (long long)PB, Cc);
}

// Round 5
// 682.356 us; speedup vs baseline: 17.3338x; 1.0513x over previous
//
#include <hip/hip_runtime.h>

constexpr int Cc = 512;
constexpr int Nn = 4096;   // 64*64
constexpr int Bb = 4;
#define EPS 1e-5f

using bf16x8 = __attribute__((ext_vector_type(8))) short;
using f32x4  = __attribute__((ext_vector_type(4))) float;
typedef unsigned short us;

__device__ __forceinline__ us f2bf(float f) {
    union { float f; unsigned int u; } v; v.f = f;
    unsigned int r = v.u + 0x7fffu + ((v.u >> 16) & 1u);   // RNE
    return (us)(r >> 16);
}
__device__ __forceinline__ float bf2f(us h) {
    union { unsigned int u; float f; } v; v.u = ((unsigned int)h) << 16;
    return v.f;
}
__device__ __forceinline__ void gload_lds16(const void* g, void* l) {
    __builtin_amdgcn_global_load_lds(
        (const __attribute__((address_space(1))) void*)g,
        (__attribute__((address_space(3))) void*)l, 16, 0, 0);
}

// ---------------- stats: per (b,c) mean & rstd (unbiased var) ----------------
__global__ __launch_bounds__(256) void stats_kernel(const float* __restrict__ x,
                                                    float* __restrict__ mean,
                                                    float* __restrict__ rstd) {
    int bc = blockIdx.x;
    const float* row = x + (size_t)bc * Nn;
    float s = 0.f, sq = 0.f;
    for (int i = threadIdx.x * 4; i < Nn; i += 256 * 4) {
        float4 v = *reinterpret_cast<const float4*>(row + i);
        s  += v.x + v.y + v.z + v.w;
        sq += v.x*v.x + v.y*v.y + v.z*v.z + v.w*v.w;
    }
    for (int off = 32; off; off >>= 1) {
        s  += __shfl_down(s, off);
        sq += __shfl_down(sq, off);
    }
    __shared__ float ls[4], lsq[4];
    int wid = threadIdx.x >> 6;
    if ((threadIdx.x & 63) == 0) { ls[wid] = s; lsq[wid] = sq; }
    __syncthreads();
    if (threadIdx.x == 0) {
        float S  = ls[0] + ls[1] + ls[2] + ls[3];
        float SQ = lsq[0] + lsq[1] + lsq[2] + lsq[3];
        float m  = S / (float)Nn;
        float var = (SQ - S * m) / (float)(Nn - 1);
        mean[bc] = m;
        rstd[bc] = rsqrtf(var + EPS);
    }
}

// ------ pack fp32 [b][c][n] -> bf16 (hi[,lo]) transposed [b][n][c], fused norm ------
template <bool NORM, bool SPLIT>
__global__ __launch_bounds__(256) void pack_T(const float* __restrict__ X,
                                              const float* __restrict__ mean,
                                              const float* __restrict__ rstd,
                                              us* __restrict__ Thi,
                                              us* __restrict__ Tlo) {
    int b = blockIdx.z;
    int n0 = blockIdx.x * 64, c0 = blockIdx.y * 64;
    __shared__ float tile[64][65];
    const float* Xb = X + (size_t)b * Cc * Nn;
    for (int i = threadIdx.x; i < 64 * 64; i += 256) {
        int c = i >> 6, n = i & 63;
        float v = Xb[(size_t)(c0 + c) * Nn + n0 + n];
        if constexpr (NORM) {
            int cg = b * Cc + c0 + c;
            v = (v - mean[cg]) * rstd[cg];
        }
        tile[c][n] = v;
    }
    __syncthreads();
    us* Hb = Thi + (size_t)b * Nn * Cc;
    for (int i = threadIdx.x; i < 64 * 64; i += 256) {
        int n = i >> 6, c = i & 63;
        float x = tile[c][n];
        us hi = f2bf(x);
        Hb[(size_t)(n0 + n) * Cc + c0 + c] = hi;
        if constexpr (SPLIT) {
            us lo = f2bf(x - bf2f(hi));
            (Tlo + (size_t)b * Nn * Cc)[(size_t)(n0 + n) * Cc + c0 + c] = lo;
        }
    }
}

// ------ pack the four 512x512 weights: f,g split hi/lo; h,o plain bf16 ------
__global__ __launch_bounds__(256) void pack_w(const float* __restrict__ fw, const float* __restrict__ gw,
                                              const float* __restrict__ hw, const float* __restrict__ ow,
                                              us* __restrict__ fh, us* __restrict__ fl,
                                              us* __restrict__ gh, us* __restrict__ gl,
                                              us* __restrict__ hb, us* __restrict__ ob) {
    int i = blockIdx.x * 256 + threadIdx.x;
    if (i >= Cc * Cc) return;
    float v = fw[i]; us hi = f2bf(v); fh[i] = hi; fl[i] = f2bf(v - bf2f(hi));
    v = gw[i]; hi = f2bf(v); gh[i] = hi; gl[i] = f2bf(v - bf2f(hi));
    hb[i] = f2bf(hw[i]);
    ob[i] = f2bf(ow[i]);
}

// ------------- MFMA GEMM: C[m][n'] = sum_k A[m][k]*B[n'][k] -------------
// A m-major (lda), B n'-major (ldb). BMxBN tile, BK per barrier pair
// (staged as BK/32 sub-tiles, each [row][32]), 4 waves (2x2),
// wave tile (BM/2)x(BN/2) in 16x16x32 frags.
// SPLIT: hi/lo planes, acc = Ah*Bh + Ah*Bl + Al*Bh (Ootomo split).
// EPI: 0 fp32, 1 bf16, 2 split hi/lo.  BIAS: 0 none, 1 bias[row], 2 bias[col].
// SWZ: chunked XCD swizzle of the linearized block id (requires nwg % 8 == 0).
template <bool SPLIT, int EPI, int BIAS, bool RESID, int BM, int BN, int BK, bool SWZ>
__global__ __launch_bounds__(256) void mfma_gemm(
    const us* __restrict__ Ahi, const us* __restrict__ Alo, int lda, long long strideA,
    const us* __restrict__ Bhi, const us* __restrict__ Blo, int ldb, long long strideB,
    void* __restrict__ out0, void* __restrict__ out1, int ldc, long long strideC,
    const float* __restrict__ bias, const float* __restrict__ resid, long long strideR,
    int K) {
    constexpr int WM = BM / 2, WN = BN / 2;
    constexpr int MI = WM / 16, NI = WN / 16;
    constexpr int AE = BM * BK, BE = BN * BK;   // elems per staged tile
    constexpr int ACH = AE / 512, BCH = BE / 512;
    __shared__ us smem[SPLIT ? 2 * (AE + BE) : (AE + BE)];
    us* As_hi = smem;
    us* Bs_hi = smem + AE;
    us* As_lo = nullptr;
    us* Bs_lo = nullptr;
    if constexpr (SPLIT) { As_lo = smem + AE + BE; Bs_lo = As_lo + AE; }

    int bz = blockIdx.z;
    const us* Ah = Ahi + (size_t)bz * strideA;
    const us* Bh = Bhi + (size_t)bz * strideB;
    const us* Al = nullptr;
    const us* Bl = nullptr;
    if constexpr (SPLIT) { Al = Alo + (size_t)bz * strideA; Bl = Blo + (size_t)bz * strideB; }

    int bx = blockIdx.x, by = blockIdx.y;
    if constexpr (SWZ) {
        int nwg = gridDim.x * gridDim.y;          // must be % 8 == 0
        int bid = blockIdx.x + gridDim.x * blockIdx.y;
        int cpx = nwg >> 3;
        int swz = (bid & 7) * cpx + (bid >> 3);
        bx = swz % gridDim.x;
        by = swz / gridDim.x;
    }
    int m0 = by * BM, n0 = bx * BN;
    int tid = threadIdx.x, wave = tid >> 6, lane = tid & 63;
    int wr = wave >> 1, wc = wave & 1;
    int lr = lane & 15, lg = lane >> 4;

    f32x4 acc[MI][NI];
#pragma unroll
    for (int i = 0; i < MI; ++i)
#pragma unroll
        for (int j = 0; j < NI; ++j) acc[i][j] = (f32x4){0.f, 0.f, 0.f, 0.f};

    for (int k0 = 0; k0 < K; k0 += BK) {
        __syncthreads();
        // stage: 1KB chunks; sub-tile kb is [BM][32] at As + kb*BM*32
#pragma unroll
        for (int ch = wave; ch < ACH; ch += 4) {
            int e0 = ch * 512 + lane * 8;
            int kb = e0 / (BM * 32);
            int rem = e0 - kb * (BM * 32);
            int rr = rem >> 5, cc = rem & 31;
            const size_t ga = (size_t)(m0 + rr) * lda + k0 + kb * 32 + cc;
            gload_lds16(Ah + ga, As_hi + ch * 512);
            if constexpr (SPLIT) gload_lds16(Al + ga, As_lo + ch * 512);
        }
#pragma unroll
        for (int ch = wave; ch < BCH; ch += 4) {
            int e0 = ch * 512 + lane * 8;
            int kb = e0 / (BN * 32);
            int rem = e0 - kb * (BN * 32);
            int rr = rem >> 5, cc = rem & 31;
            const size_t gb = (size_t)(n0 + rr) * ldb + k0 + kb * 32 + cc;
            gload_lds16(Bh + gb, Bs_hi + ch * 512);
            if constexpr (SPLIT) gload_lds16(Bl + gb, Bs_lo + ch * 512);
        }
        asm volatile("s_waitcnt vmcnt(0)" ::: "memory");
        __syncthreads();

#pragma unroll
        for (int kb = 0; kb < BK / 32; ++kb) {
            bf16x8 ah[MI], bh[NI];
#pragma unroll
            for (int x = 0; x < MI; ++x)
                ah[x] = *reinterpret_cast<const bf16x8*>(
                    &As_hi[kb * BM * 32 + (wr * WM + x * 16 + lr) * 32 + lg * 8]);
#pragma unroll
            for (int x = 0; x < NI; ++x)
                bh[x] = *reinterpret_cast<const bf16x8*>(
                    &Bs_hi[kb * BN * 32 + (wc * WN + x * 16 + lr) * 32 + lg * 8]);
            if constexpr (SPLIT) {
                bf16x8 al[MI], bl[NI];
#pragma unroll
                for (int x = 0; x < MI; ++x)
                    al[x] = *reinterpret_cast<const bf16x8*>(
                        &As_lo[kb * BM * 32 + (wr * WM + x * 16 + lr) * 32 + lg * 8]);
#pragma unroll
                for (int x = 0; x < NI; ++x)
                    bl[x] = *reinterpret_cast<const bf16x8*>(
                        &Bs_lo[kb * BN * 32 + (wc * WN + x * 16 + lr) * 32 + lg * 8]);
#pragma unroll
                for (int mi = 0; mi < MI; ++mi)
#pragma unroll
                    for (int ni = 0; ni < NI; ++ni) {
                        acc[mi][ni] = __builtin_amdgcn_mfma_f32_16x16x32_bf16(ah[mi], bh[ni], acc[mi][ni], 0, 0, 0);
                        acc[mi][ni] = __builtin_amdgcn_mfma_f32_16x16x32_bf16(ah[mi], bl[ni], acc[mi][ni], 0, 0, 0);
                        acc[mi][ni] = __builtin_amdgcn_mfma_f32_16x16x32_bf16(al[mi], bh[ni], acc[mi][ni], 0, 0, 0);
                    }
            } else {
#pragma unroll
                for (int mi = 0; mi < MI; ++mi)
#pragma unroll
                    for (int ni = 0; ni < NI; ++ni)
                        acc[mi][ni] = __builtin_amdgcn_mfma_f32_16x16x32_bf16(ah[mi], bh[ni], acc[mi][ni], 0, 0, 0);
            }
        }
    }
    // epilogue: frag D element (lg*4+r, lr)
#pragma unroll
    for (int mi = 0; mi < MI; ++mi) {
        int row = m0 + wr * WM + mi * 16 + lg * 4;
#pragma unroll
        for (int ni = 0; ni < NI; ++ni) {
            int col = n0 + wc * WN + ni * 16 + lr;
#pragma unroll
            for (int r = 0; r < 4; ++r) {
                float v = acc[mi][ni][r];
                if constexpr (BIAS == 1) v += bias[row + r];
                if constexpr (BIAS == 2) v += bias[col];
                if constexpr (RESID)
                    v += resid[(size_t)bz * strideR + (size_t)(row + r) * ldc + col];
                size_t off = (size_t)bz * strideC + (size_t)(row + r) * ldc + col;
                if constexpr (EPI == 0) {
                    ((float*)out0)[off] = v;
                } else if constexpr (EPI == 1) {
                    ((us*)out0)[off] = f2bf(v);
                } else {
                    us hi = f2bf(v);
                    ((us*)out0)[off] = hi;
                    ((us*)out1)[off] = f2bf(v - bf2f(hi));
                }
            }
        }
    }
}

// ------------- row softmax fp32 -> normalized P bf16 -------------
__global__ __launch_bounds__(256) void softmax_kernel(const float* __restrict__ S,
                                                      us* __restrict__ P) {
    int row = blockIdx.x;
    const float4* r4 = reinterpret_cast<const float4*>(S + (size_t)row * Nn);
    int t = threadIdx.x;
    float4 v[4];
    float mx = -1e30f;
#pragma unroll
    for (int j = 0; j < 4; ++j) {
        v[j] = r4[t + 256 * j];
        mx = fmaxf(mx, fmaxf(fmaxf(v[j].x, v[j].y), fmaxf(v[j].z, v[j].w)));
    }
    for (int off = 32; off; off >>= 1) mx = fmaxf(mx, __shfl_down(mx, off));
    __shared__ float redm[4], reds[4];
    int wid = t >> 6;
    if ((t & 63) == 0) redm[wid] = mx;
    __syncthreads();
    mx = fmaxf(fmaxf(redm[0], redm[1]), fmaxf(redm[2], redm[3]));
    float s = 0.f;
#pragma unroll
    for (int j = 0; j < 4; ++j) {
        v[j].x = __expf(v[j].x - mx); v[j].y = __expf(v[j].y - mx);
        v[j].z = __expf(v[j].z - mx); v[j].w = __expf(v[j].w - mx);
        s += v[j].x + v[j].y + v[j].z + v[j].w;
    }
    for (int off = 32; off; off >>= 1) s += __shfl_down(s, off);
    if ((t & 63) == 0) reds[wid] = s;
    __syncthreads();
    s = reds[0] + reds[1] + reds[2] + reds[3];
    float inv = 1.f / s;
    unsigned long long* P8 = reinterpret_cast<unsigned long long*>(P + (size_t)row * Nn);
#pragma unroll
    for (int j = 0; j < 4; ++j) {
        unsigned long long pk = (unsigned long long)f2bf(v[j].x * inv)
            | ((unsigned long long)f2bf(v[j].y * inv) << 16)
            | ((unsigned long long)f2bf(v[j].z * inv) << 32)
            | ((unsigned long long)f2bf(v[j].w * inv) << 48);
        P8[t + 256 * j] = pk;
    }
}

extern "C" void kernel_launch(void* const* d_in, const int* in_sizes, int n_in,
                              void* d_out, int out_size, void* d_ws, size_t ws_size,
                              hipStream_t stream) {
    const float* content = (const float*)d_in[0];
    const float* style   = (const float*)d_in[1];
    const float* f_w = (const float*)d_in[2];
    const float* f_b = (const float*)d_in[3];
    const float* g_w = (const float*)d_in[4];
    const float* g_b = (const float*)d_in[5];
    const float* h_w = (const float*)d_in[6];
    const float* h_b = (const float*)d_in[7];
    const float* o_w = (const float*)d_in[8];
    const float* o_b = (const float*)d_in[9];
    float* out = (float*)d_out;
    char* ws = (char*)d_ws;

    const size_t PB  = (size_t)Cc * Nn;        // 2,097,152 elems per batch-plane
    const size_t TEN = PB * Bb;                // 8,388,608 elems (16 MB as bf16)

    // region A [0,80MB): packed inputs; reused as S fp32 [0,64MB) after convs
    us* CNhi = (us*)ws;
    us* CNlo = CNhi + TEN;
    us* SNhi = CNlo + TEN;
    us* SNlo = SNhi + TEN;
    us* SR   = SNlo + TEN;
    float* S_buf = (float*)ws;                 // 64MB overlay (CN+SN dead by then)
    // region B [80,176MB): conv outputs
    us* FThi = SR + TEN;
    us* FTlo = FThi + TEN;
    us* GThi = FTlo + TEN;
    us* GTlo = GThi + TEN;
    us* Hbf  = GTlo + TEN;
    us* OT   = Hbf + TEN;
    // region C: packed weights + stats + P (per-batch, 32MB)
    us* fwh = OT + TEN;
    us* fwl = fwh + Cc * Cc;
    us* gwh = fwl + Cc * Cc;
    us* gwl = gwh + Cc * Cc;
    us* hwb = gwl + Cc * Cc;
    us* owb = hwb + Cc * Cc;
    float* meanC = (float*)(owb + Cc * Cc);
    float* rstdC = meanC + Bb * Cc;
    float* meanS = rstdC + Bb * Cc;
    float* rstdS = meanS + Bb * Cc;
    us* P = (us*)(rstdS + Bb * Cc);

    stats_kernel<<<Bb * Cc, 256, 0, stream>>>(content, meanC, rstdC);
    stats_kernel<<<Bb * Cc, 256, 0, stream>>>(style, meanS, rstdS);

    dim3 pgrid(Nn / 64, Cc / 64, Bb);
    pack_T<true, true><<<pgrid, 256, 0, stream>>>(content, meanC, rstdC, CNhi, CNlo);
    pack_T<true, true><<<pgrid, 256, 0, stream>>>(style, meanS, rstdS, SNhi, SNlo);
    pack_T<false, false><<<pgrid, 256, 0, stream>>>(style, nullptr, nullptr, SR, nullptr);
    pack_w<<<(Cc * Cc + 255) / 256, 256, 0, stream>>>(f_w, g_w, h_w, o_w,
                                                      fwh, fwl, gwh, gwl, hwb, owb);

    // F^T[q][c'] = sum_c CN[q][c] f_w[c'][c] + f_b[c']   (M=4096, N=512, K=512)
    mfma_gemm<true, 2, 2, false, 128, 128, 32, false><<<dim3(4, 32, Bb), 256, 0, stream>>>(
        CNhi, CNlo, Cc, (long long)PB, fwh, fwl, Cc, 0,
        FThi, FTlo, Cc, (long long)PB, f_b, nullptr, 0, Cc);
    // G^T likewise
    mfma_gemm<true, 2, 2, false, 128, 128, 32, false><<<dim3(4, 32, Bb), 256, 0, stream>>>(
        SNhi, SNlo, Cc, (long long)PB, gwh, gwl, Cc, 0,
        GThi, GTlo, Cc, (long long)PB, g_b, nullptr, 0, Cc);
    // H[c'][s] = sum_c h_w[c'][c] SR[s][c] + h_b[c']    (M=512, N=4096, K=512)
    mfma_gemm<false, 1, 1, false, 128, 128, 32, false><<<dim3(32, 4, Bb), 256, 0, stream>>>(
        hwb, nullptr, Cc, 0, SR, nullptr, Cc, (long long)PB,
        Hbf, nullptr, Nn, (long long)PB, h_b, nullptr, 0, Cc);

    for (int b = 0; b < Bb; ++b) {
        const size_t tb = (size_t)b * PB;
        // S[q][s] = sum_c F^T[q][c] G^T[s][c]   (M=N=4096, K=512), split 3-pass
        mfma_gemm<true, 0, 0, false, 128, 128, 32, true><<<dim3(32, 32, 1), 256, 0, stream>>>(
            FThi + tb, FTlo + tb, Cc, 0, GThi + tb, GTlo + tb, Cc, 0,
            S_buf, nullptr, Nn, 0, nullptr, nullptr, 0, Cc);
        softmax_kernel<<<Nn, 256, 0, stream>>>(S_buf, P);
        // O^T[q][c'] = sum_s P[q][s] H[c'][s]   (M=4096, N=512, K=4096)
        // 64x64 tiles, BK=64, chunked XCD swizzle for P row-tile L2 reuse
        mfma_gemm<false, 1, 0, false, 64, 64, 64, true><<<dim3(Cc / 64, Nn / 64, 1), 256, 0, stream>>>(
            P, nullptr, Nn, 0, Hbf + tb, nullptr, Nn, 0,
            OT + tb, nullptr, Cc, 0, nullptr, nullptr, 0, Nn);
    }

    // out[c'][n] = sum_c o_w[c'][c] O^T[n][c] + o_b[c'] + content[c'][n]
    mfma_gemm<false, 0, 1, true, 128, 128, 32, false><<<dim3(32, 4, Bb), 256, 0, stream>>>(
        owb, nullptr, Cc, 0, OT, nullptr, Cc, (long long)PB,
        out, nullptr, Nn, (long long)PB, o_b, content, (long long)PB, Cc);
}

// Round 6
// 512.330 us; speedup vs baseline: 23.0863x; 1.3319x over previous
//
#include <hip/hip_runtime.h>

constexpr int Cc = 512;
constexpr int Nn = 4096;   // 64*64
constexpr int Bb = 4;
#define EPS 1e-5f

using bf16x8 = __attribute__((ext_vector_type(8))) short;
using f16x8  = __attribute__((ext_vector_type(8))) _Float16;
using f32x4  = __attribute__((ext_vector_type(4))) float;
typedef unsigned short us;

__device__ __forceinline__ us f2bf(float f) {
    union { float f; unsigned int u; } v; v.f = f;
    unsigned int r = v.u + 0x7fffu + ((v.u >> 16) & 1u);   // RNE
    return (us)(r >> 16);
}
__device__ __forceinline__ float bf2f(us h) {
    union { unsigned int u; float f; } v; v.u = ((unsigned int)h) << 16;
    return v.f;
}
__device__ __forceinline__ us f2h(float f) {
    union { _Float16 h; us u; } v; v.h = (_Float16)f;
    return v.u;
}
__device__ __forceinline__ void gload_lds16(const void* g, void* l) {
    __builtin_amdgcn_global_load_lds(
        (const __attribute__((address_space(1))) void*)g,
        (__attribute__((address_space(3))) void*)l, 16, 0, 0);
}

// ---------------- stats: per (b,c) mean & rstd (unbiased var) ----------------
__global__ __launch_bounds__(256) void stats_kernel(const float* __restrict__ x,
                                                    float* __restrict__ mean,
                                                    float* __restrict__ rstd) {
    int bc = blockIdx.x;
    const float* row = x + (size_t)bc * Nn;
    float s = 0.f, sq = 0.f;
    for (int i = threadIdx.x * 4; i < Nn; i += 256 * 4) {
        float4 v = *reinterpret_cast<const float4*>(row + i);
        s  += v.x + v.y + v.z + v.w;
        sq += v.x*v.x + v.y*v.y + v.z*v.z + v.w*v.w;
    }
    for (int off = 32; off; off >>= 1) {
        s  += __shfl_down(s, off);
        sq += __shfl_down(sq, off);
    }
    __shared__ float ls[4], lsq[4];
    int wid = threadIdx.x >> 6;
    if ((threadIdx.x & 63) == 0) { ls[wid] = s; lsq[wid] = sq; }
    __syncthreads();
    if (threadIdx.x == 0) {
        float S  = ls[0] + ls[1] + ls[2] + ls[3];
        float SQ = lsq[0] + lsq[1] + lsq[2] + lsq[3];
        float m  = S / (float)Nn;
        float var = (SQ - S * m) / (float)(Nn - 1);
        mean[bc] = m;
        rstd[bc] = rsqrtf(var + EPS);
    }
}

// ------ pack fp32 [b][c][n] -> transposed [b][n][c]; bf16 hi/lo or fp16 ------
// MODE 0: bf16 split (hi,lo) with NORM;  MODE 1: fp16 single, no norm.
template <int MODE>
__global__ __launch_bounds__(256) void pack_T(const float* __restrict__ X,
                                              const float* __restrict__ mean,
                                              const float* __restrict__ rstd,
                                              us* __restrict__ T0,
                                              us* __restrict__ T1) {
    int b = blockIdx.z;
    int n0 = blockIdx.x * 64, c0 = blockIdx.y * 64;
    __shared__ float tile[64][65];
    const float* Xb = X + (size_t)b * Cc * Nn;
    for (int i = threadIdx.x; i < 64 * 64; i += 256) {
        int c = i >> 6, n = i & 63;
        float v = Xb[(size_t)(c0 + c) * Nn + n0 + n];
        if constexpr (MODE == 0) {
            int cg = b * Cc + c0 + c;
            v = (v - mean[cg]) * rstd[cg];
        }
        tile[c][n] = v;
    }
    __syncthreads();
    us* Pb = T0 + (size_t)b * Nn * Cc;
    for (int i = threadIdx.x; i < 64 * 64; i += 256) {
        int n = i >> 6, c = i & 63;
        float x = tile[c][n];
        size_t off = (size_t)(n0 + n) * Cc + c0 + c;
        if constexpr (MODE == 0) {
            us hi = f2bf(x);
            Pb[off] = hi;
            (T1 + (size_t)b * Nn * Cc)[off] = f2bf(x - bf2f(hi));
        } else {
            Pb[off] = f2h(x);
        }
    }
}

// ------ pack weights: f,g split bf16 hi/lo; h,o fp16 ------
__global__ __launch_bounds__(256) void pack_w(const float* __restrict__ fw, const float* __restrict__ gw,
                                              const float* __restrict__ hw, const float* __restrict__ ow,
                                              us* __restrict__ fh, us* __restrict__ fl,
                                              us* __restrict__ gh, us* __restrict__ gl,
                                              us* __restrict__ hb, us* __restrict__ ob) {
    int i = blockIdx.x * 256 + threadIdx.x;
    if (i >= Cc * Cc) return;
    float v = fw[i]; us hi = f2bf(v); fh[i] = hi; fl[i] = f2bf(v - bf2f(hi));
    v = gw[i]; hi = f2bf(v); gh[i] = hi; gl[i] = f2bf(v - bf2f(hi));
    hb[i] = f2h(hw[i]);
    ob[i] = f2h(ow[i]);
}

// ------------- MFMA GEMM: C[m][n'] = sum_k A[m][k]*B[n'][k] -------------
// A m-major (lda), B n'-major (ldb). BMxBN tile, BK per barrier pair
// (BK/32 sub-tiles [row][32]), 4 waves (2x2), frags 16x16x32.
// SPLIT (bf16 only): hi/lo planes, acc = Ah*Bh + Ah*Bl + Al*Bh.
// F16: inputs are fp16, single plane, mfma_f32_16x16x32_f16.
// EPI: 0 fp32 store, 1 fp16 store.  BIAS: 0 none, 1 bias[row], 2 bias[col].
// SWZ: chunked XCD swizzle of the linearized block id (requires nwg % 8 == 0).
template <bool SPLIT, int EPI, int BIAS, bool RESID, int BM, int BN, int BK, bool SWZ, bool F16>
__global__ __launch_bounds__(256) void mfma_gemm(
    const us* __restrict__ Ahi, const us* __restrict__ Alo, int lda, long long strideA,
    const us* __restrict__ Bhi, const us* __restrict__ Blo, int ldb, long long strideB,
    void* __restrict__ out0, int ldc, long long strideC,
    const float* __restrict__ bias, const float* __restrict__ resid, long long strideR,
    int K) {
    constexpr int WM = BM / 2, WN = BN / 2;
    constexpr int MI = WM / 16, NI = WN / 16;
    constexpr int AE = BM * BK, BE = BN * BK;   // elems per staged tile
    constexpr int ACH = AE / 512, BCH = BE / 512;
    __shared__ us smem[SPLIT ? 2 * (AE + BE) : (AE + BE)];
    us* As_hi = smem;
    us* Bs_hi = smem + AE;
    us* As_lo = nullptr;
    us* Bs_lo = nullptr;
    if constexpr (SPLIT) { As_lo = smem + AE + BE; Bs_lo = As_lo + AE; }

    int bz = blockIdx.z;
    const us* Ah = Ahi + (size_t)bz * strideA;
    const us* Bh = Bhi + (size_t)bz * strideB;
    const us* Al = nullptr;
    const us* Bl = nullptr;
    if constexpr (SPLIT) { Al = Alo + (size_t)bz * strideA; Bl = Blo + (size_t)bz * strideB; }

    int bx = blockIdx.x, by = blockIdx.y;
    if constexpr (SWZ) {
        int nwg = gridDim.x * gridDim.y;          // must be % 8 == 0
        int bid = blockIdx.x + gridDim.x * blockIdx.y;
        int cpx = nwg >> 3;
        int swz = (bid & 7) * cpx + (bid >> 3);
        bx = swz % gridDim.x;
        by = swz / gridDim.x;
    }
    int m0 = by * BM, n0 = bx * BN;
    int tid = threadIdx.x, wave = tid >> 6, lane = tid & 63;
    int wr = wave >> 1, wc = wave & 1;
    int lr = lane & 15, lg = lane >> 4;

    f32x4 acc[MI][NI];
#pragma unroll
    for (int i = 0; i < MI; ++i)
#pragma unroll
        for (int j = 0; j < NI; ++j) acc[i][j] = (f32x4){0.f, 0.f, 0.f, 0.f};

    for (int k0 = 0; k0 < K; k0 += BK) {
        __syncthreads();
        // stage: 1KB chunks; sub-tile kb is [rows][32] at base + kb*rows*32
#pragma unroll
        for (int ch = wave; ch < ACH; ch += 4) {
            int e0 = ch * 512 + lane * 8;
            int kb = e0 / (BM * 32);
            int rem = e0 - kb * (BM * 32);
            int rr = rem >> 5, cc = rem & 31;
            const size_t ga = (size_t)(m0 + rr) * lda + k0 + kb * 32 + cc;
            gload_lds16(Ah + ga, As_hi + ch * 512);
            if constexpr (SPLIT) gload_lds16(Al + ga, As_lo + ch * 512);
        }
#pragma unroll
        for (int ch = wave; ch < BCH; ch += 4) {
            int e0 = ch * 512 + lane * 8;
            int kb = e0 / (BN * 32);
            int rem = e0 - kb * (BN * 32);
            int rr = rem >> 5, cc = rem & 31;
            const size_t gb = (size_t)(n0 + rr) * ldb + k0 + kb * 32 + cc;
            gload_lds16(Bh + gb, Bs_hi + ch * 512);
            if constexpr (SPLIT) gload_lds16(Bl + gb, Bs_lo + ch * 512);
        }
        asm volatile("s_waitcnt vmcnt(0)" ::: "memory");
        __syncthreads();

#pragma unroll
        for (int kb = 0; kb < BK / 32; ++kb) {
            const us* Abase = As_hi + kb * BM * 32;
            const us* Bbase = Bs_hi + kb * BN * 32;
            if constexpr (F16) {
                f16x8 a[MI], b[NI];
#pragma unroll
                for (int x = 0; x < MI; ++x)
                    a[x] = *reinterpret_cast<const f16x8*>(&Abase[(wr * WM + x * 16 + lr) * 32 + lg * 8]);
#pragma unroll
                for (int x = 0; x < NI; ++x)
                    b[x] = *reinterpret_cast<const f16x8*>(&Bbase[(wc * WN + x * 16 + lr) * 32 + lg * 8]);
#pragma unroll
                for (int mi = 0; mi < MI; ++mi)
#pragma unroll
                    for (int ni = 0; ni < NI; ++ni)
                        acc[mi][ni] = __builtin_amdgcn_mfma_f32_16x16x32_f16(a[mi], b[ni], acc[mi][ni], 0, 0, 0);
            } else if constexpr (SPLIT) {
                bf16x8 ah[MI], bh[NI], al[MI], bl[NI];
#pragma unroll
                for (int x = 0; x < MI; ++x) {
                    ah[x] = *reinterpret_cast<const bf16x8*>(&Abase[(wr * WM + x * 16 + lr) * 32 + lg * 8]);
                    al[x] = *reinterpret_cast<const bf16x8*>(&As_lo[kb * BM * 32 + (wr * WM + x * 16 + lr) * 32 + lg * 8]);
                }
#pragma unroll
                for (int x = 0; x < NI; ++x) {
                    bh[x] = *reinterpret_cast<const bf16x8*>(&Bbase[(wc * WN + x * 16 + lr) * 32 + lg * 8]);
                    bl[x] = *reinterpret_cast<const bf16x8*>(&Bs_lo[kb * BN * 32 + (wc * WN + x * 16 + lr) * 32 + lg * 8]);
                }
#pragma unroll
                for (int mi = 0; mi < MI; ++mi)
#pragma unroll
                    for (int ni = 0; ni < NI; ++ni) {
                        acc[mi][ni] = __builtin_amdgcn_mfma_f32_16x16x32_bf16(ah[mi], bh[ni], acc[mi][ni], 0, 0, 0);
                        acc[mi][ni] = __builtin_amdgcn_mfma_f32_16x16x32_bf16(ah[mi], bl[ni], acc[mi][ni], 0, 0, 0);
                        acc[mi][ni] = __builtin_amdgcn_mfma_f32_16x16x32_bf16(al[mi], bh[ni], acc[mi][ni], 0, 0, 0);
                    }
            } else {
                bf16x8 ah[MI], bh[NI];
#pragma unroll
                for (int x = 0; x < MI; ++x)
                    ah[x] = *reinterpret_cast<const bf16x8*>(&Abase[(wr * WM + x * 16 + lr) * 32 + lg * 8]);
#pragma unroll
                for (int x = 0; x < NI; ++x)
                    bh[x] = *reinterpret_cast<const bf16x8*>(&Bbase[(wc * WN + x * 16 + lr) * 32 + lg * 8]);
#pragma unroll
                for (int mi = 0; mi < MI; ++mi)
#pragma unroll
                    for (int ni = 0; ni < NI; ++ni)
                        acc[mi][ni] = __builtin_amdgcn_mfma_f32_16x16x32_bf16(ah[mi], bh[ni], acc[mi][ni], 0, 0, 0);
            }
        }
    }
    // epilogue: frag D element (lg*4+r, lr)
#pragma unroll
    for (int mi = 0; mi < MI; ++mi) {
        int row = m0 + wr * WM + mi * 16 + lg * 4;
#pragma unroll
        for (int ni = 0; ni < NI; ++ni) {
            int col = n0 + wc * WN + ni * 16 + lr;
#pragma unroll
            for (int r = 0; r < 4; ++r) {
                float v = acc[mi][ni][r];
                if constexpr (BIAS == 1) v += bias[row + r];
                if constexpr (BIAS == 2) v += bias[col];
                if constexpr (RESID)
                    v += resid[(size_t)bz * strideR + (size_t)(row + r) * ldc + col];
                size_t off = (size_t)bz * strideC + (size_t)(row + r) * ldc + col;
                if constexpr (EPI == 0) {
                    ((float*)out0)[off] = v;
                } else {
                    ((us*)out0)[off] = f2h(v);
                }
            }
        }
    }
}

// ------------- row softmax fp32 -> normalized P fp16 -------------
__global__ __launch_bounds__(256) void softmax_kernel(const float* __restrict__ S,
                                                      us* __restrict__ P) {
    int row = blockIdx.x;
    const float4* r4 = reinterpret_cast<const float4*>(S + (size_t)row * Nn);
    int t = threadIdx.x;
    float4 v[4];
    float mx = -1e30f;
#pragma unroll
    for (int j = 0; j < 4; ++j) {
        v[j] = r4[t + 256 * j];
        mx = fmaxf(mx, fmaxf(fmaxf(v[j].x, v[j].y), fmaxf(v[j].z, v[j].w)));
    }
    for (int off = 32; off; off >>= 1) mx = fmaxf(mx, __shfl_down(mx, off));
    __shared__ float redm[4], reds[4];
    int wid = t >> 6;
    if ((t & 63) == 0) redm[wid] = mx;
    __syncthreads();
    mx = fmaxf(fmaxf(redm[0], redm[1]), fmaxf(redm[2], redm[3]));
    float s = 0.f;
#pragma unroll
    for (int j = 0; j < 4; ++j) {
        v[j].x = __expf(v[j].x - mx); v[j].y = __expf(v[j].y - mx);
        v[j].z = __expf(v[j].z - mx); v[j].w = __expf(v[j].w - mx);
        s += v[j].x + v[j].y + v[j].z + v[j].w;
    }
    for (int off = 32; off; off >>= 1) s += __shfl_down(s, off);
    if ((t & 63) == 0) reds[wid] = s;
    __syncthreads();
    s = reds[0] + reds[1] + reds[2] + reds[3];
    float inv = 1.f / s;
    unsigned long long* P8 = reinterpret_cast<unsigned long long*>(P + (size_t)row * Nn);
#pragma unroll
    for (int j = 0; j < 4; ++j) {
        unsigned long long pk = (unsigned long long)f2h(v[j].x * inv)
            | ((unsigned long long)f2h(v[j].y * inv) << 16)
            | ((unsigned long long)f2h(v[j].z * inv) << 32)
            | ((unsigned long long)f2h(v[j].w * inv) << 48);
        P8[t + 256 * j] = pk;
    }
}

extern "C" void kernel_launch(void* const* d_in, const int* in_sizes, int n_in,
                              void* d_out, int out_size, void* d_ws, size_t ws_size,
                              hipStream_t stream) {
    const float* content = (const float*)d_in[0];
    const float* style   = (const float*)d_in[1];
    const float* f_w = (const float*)d_in[2];
    const float* f_b = (const float*)d_in[3];
    const float* g_w = (const float*)d_in[4];
    const float* g_b = (const float*)d_in[5];
    const float* h_w = (const float*)d_in[6];
    const float* h_b = (const float*)d_in[7];
    const float* o_w = (const float*)d_in[8];
    const float* o_b = (const float*)d_in[9];
    float* out = (float*)d_out;
    char* ws = (char*)d_ws;

    const size_t PB  = (size_t)Cc * Nn;        // 2,097,152 elems per batch-plane
    const size_t TEN = PB * Bb;                // 8,388,608 elems (16 MB as 16-bit)

    // region A [0,80MB): packed inputs; first 64MB reused as S fp32 after convs
    us* CNhi = (us*)ws;
    us* CNlo = CNhi + TEN;
    us* SNhi = CNlo + TEN;
    us* SNlo = SNhi + TEN;
    us* SR   = SNlo + TEN;                     // style raw, fp16
    float* S_buf = (float*)ws;                 // 64MB overlay (CN+SN dead by then)
    // region B [80,144MB): conv outputs (fp16)
    us* FT  = SR + TEN;                        // F^T [q][c]
    us* GT  = FT + TEN;                        // G^T [s][c]
    us* Hbf = GT + TEN;                        // H   [c'][s]
    us* OT  = Hbf + TEN;                       // O^T [q][c']
    // region C: packed weights + stats + P (per-batch, 32MB fp16)
    us* fwh = OT + TEN;
    us* fwl = fwh + Cc * Cc;
    us* gwh = fwl + Cc * Cc;
    us* gwl = gwh + Cc * Cc;
    us* hwb = gwl + Cc * Cc;
    us* owb = hwb + Cc * Cc;
    float* meanC = (float*)(owb + Cc * Cc);
    float* rstdC = meanC + Bb * Cc;
    float* meanS = rstdC + Bb * Cc;
    float* rstdS = meanS + Bb * Cc;
    us* P = (us*)(rstdS + Bb * Cc);

    stats_kernel<<<Bb * Cc, 256, 0, stream>>>(content, meanC, rstdC);
    stats_kernel<<<Bb * Cc, 256, 0, stream>>>(style, meanS, rstdS);

    dim3 pgrid(Nn / 64, Cc / 64, Bb);
    pack_T<0><<<pgrid, 256, 0, stream>>>(content, meanC, rstdC, CNhi, CNlo);
    pack_T<0><<<pgrid, 256, 0, stream>>>(style, meanS, rstdS, SNhi, SNlo);
    pack_T<1><<<pgrid, 256, 0, stream>>>(style, nullptr, nullptr, SR, nullptr);
    pack_w<<<(Cc * Cc + 255) / 256, 256, 0, stream>>>(f_w, g_w, h_w, o_w,
                                                      fwh, fwl, gwh, gwl, hwb, owb);

    // F^T[q][c'] = sum_c CN[q][c] f_w[c'][c] + f_b[c']  (M=4096,N=512,K=512) split-bf16 -> fp16
    mfma_gemm<true, 1, 2, false, 128, 128, 32, false, false><<<dim3(4, 32, Bb), 256, 0, stream>>>(
        CNhi, CNlo, Cc, (long long)PB, fwh, fwl, Cc, 0,
        FT, Cc, (long long)PB, f_b, nullptr, 0, Cc);
    // G^T likewise
    mfma_gemm<true, 1, 2, false, 128, 128, 32, false, false><<<dim3(4, 32, Bb), 256, 0, stream>>>(
        SNhi, SNlo, Cc, (long long)PB, gwh, gwl, Cc, 0,
        GT, Cc, (long long)PB, g_b, nullptr, 0, Cc);
    // H[c'][s] = sum_c h_w[c'][c] SR[s][c] + h_b[c']   (M=512,N=4096,K=512) fp16
    mfma_gemm<false, 1, 1, false, 128, 128, 64, false, true><<<dim3(32, 4, Bb), 256, 0, stream>>>(
        hwb, nullptr, Cc, 0, SR, nullptr, Cc, (long long)PB,
        Hbf, Nn, (long long)PB, h_b, nullptr, 0, Cc);

    for (int b = 0; b < Bb; ++b) {
        const size_t tb = (size_t)b * PB;
        // S[q][s] = sum_c F^T[q][c] G^T[s][c]  (M=N=4096,K=512) fp16 single pass
        mfma_gemm<false, 0, 0, false, 128, 128, 64, true, true><<<dim3(32, 32, 1), 256, 0, stream>>>(
            FT + tb, nullptr, Cc, 0, GT + tb, nullptr, Cc, 0,
            S_buf, Nn, 0, nullptr, nullptr, 0, Cc);
        softmax_kernel<<<Nn, 256, 0, stream>>>(S_buf, P);
        // O^T[q][c'] = sum_s P[q][s] H[c'][s]  (M=4096,N=512,K=4096) fp16
        mfma_gemm<false, 1, 0, false, 64, 64, 64, true, true><<<dim3(Cc / 64, Nn / 64, 1), 256, 0, stream>>>(
            P, nullptr, Nn, 0, Hbf + tb, nullptr, Nn, 0,
            OT + tb, Cc, 0, nullptr, nullptr, 0, Nn);
    }

    // out[c'][n] = sum_c o_w[c'][c] O^T[n][c] + o_b[c'] + content[c'][n]  fp16 in, fp32 out
    mfma_gemm<false, 0, 1, true, 128, 128, 64, false, true><<<dim3(32, 4, Bb), 256, 0, stream>>>(
        owb, nullptr, Cc, 0, OT, nullptr, Cc, (long long)PB,
        out, Nn, (long long)PB, o_b, content, (long long)PB, Cc);
}

// Round 7
// 490.566 us; speedup vs baseline: 24.1106x; 1.0444x over previous
//
#include <hip/hip_runtime.h>

constexpr int Cc = 512;
constexpr int Nn = 4096;   // 64*64
constexpr int Bb = 4;
#define EPS 1e-5f

using bf16x8 = __attribute__((ext_vector_type(8))) short;
using f16x8  = __attribute__((ext_vector_type(8))) _Float16;
using f32x4  = __attribute__((ext_vector_type(4))) float;
typedef unsigned short us;

__device__ __forceinline__ us f2bf(float f) {
    union { float f; unsigned int u; } v; v.f = f;
    unsigned int r = v.u + 0x7fffu + ((v.u >> 16) & 1u);   // RNE
    return (us)(r >> 16);
}
__device__ __forceinline__ float bf2f(us h) {
    union { unsigned int u; float f; } v; v.u = ((unsigned int)h) << 16;
    return v.f;
}
__device__ __forceinline__ us f2h(float f) {
    union { _Float16 h; us u; } v; v.h = (_Float16)f;
    return v.u;
}
__device__ __forceinline__ void gload_lds16(const void* g, void* l) {
    __builtin_amdgcn_global_load_lds(
        (const __attribute__((address_space(1))) void*)g,
        (__attribute__((address_space(3))) void*)l, 16, 0, 0);
}

// ---------------- stats: per (b,c) mean & rstd (unbiased var) ----------------
__global__ __launch_bounds__(256) void stats_kernel(const float* __restrict__ x,
                                                    float* __restrict__ mean,
                                                    float* __restrict__ rstd) {
    int bc = blockIdx.x;
    const float* row = x + (size_t)bc * Nn;
    float s = 0.f, sq = 0.f;
    for (int i = threadIdx.x * 4; i < Nn; i += 256 * 4) {
        float4 v = *reinterpret_cast<const float4*>(row + i);
        s  += v.x + v.y + v.z + v.w;
        sq += v.x*v.x + v.y*v.y + v.z*v.z + v.w*v.w;
    }
    for (int off = 32; off; off >>= 1) {
        s  += __shfl_down(s, off);
        sq += __shfl_down(sq, off);
    }
    __shared__ float ls[4], lsq[4];
    int wid = threadIdx.x >> 6;
    if ((threadIdx.x & 63) == 0) { ls[wid] = s; lsq[wid] = sq; }
    __syncthreads();
    if (threadIdx.x == 0) {
        float S  = ls[0] + ls[1] + ls[2] + ls[3];
        float SQ = lsq[0] + lsq[1] + lsq[2] + lsq[3];
        float m  = S / (float)Nn;
        float var = (SQ - S * m) / (float)(Nn - 1);
        mean[bc] = m;
        rstd[bc] = rsqrtf(var + EPS);
    }
}

// ------ pack fp32 [b][c][n] -> transposed [b][n][c]; bf16 hi/lo or fp16 ------
// MODE 0: bf16 split (hi,lo) with NORM;  MODE 1: fp16 single, no norm.
template <int MODE>
__global__ __launch_bounds__(256) void pack_T(const float* __restrict__ X,
                                              const float* __restrict__ mean,
                                              const float* __restrict__ rstd,
                                              us* __restrict__ T0,
                                              us* __restrict__ T1) {
    int b = blockIdx.z;
    int n0 = blockIdx.x * 64, c0 = blockIdx.y * 64;
    __shared__ float tile[64][65];
    const float* Xb = X + (size_t)b * Cc * Nn;
    for (int i = threadIdx.x; i < 64 * 64; i += 256) {
        int c = i >> 6, n = i & 63;
        float v = Xb[(size_t)(c0 + c) * Nn + n0 + n];
        if constexpr (MODE == 0) {
            int cg = b * Cc + c0 + c;
            v = (v - mean[cg]) * rstd[cg];
        }
        tile[c][n] = v;
    }
    __syncthreads();
    us* Pb = T0 + (size_t)b * Nn * Cc;
    for (int i = threadIdx.x; i < 64 * 64; i += 256) {
        int n = i >> 6, c = i & 63;
        float x = tile[c][n];
        size_t off = (size_t)(n0 + n) * Cc + c0 + c;
        if constexpr (MODE == 0) {
            us hi = f2bf(x);
            Pb[off] = hi;
            (T1 + (size_t)b * Nn * Cc)[off] = f2bf(x - bf2f(hi));
        } else {
            Pb[off] = f2h(x);
        }
    }
}

// ------ pack weights: f,g split bf16 hi/lo; h,o fp16 ------
__global__ __launch_bounds__(256) void pack_w(const float* __restrict__ fw, const float* __restrict__ gw,
                                              const float* __restrict__ hw, const float* __restrict__ ow,
                                              us* __restrict__ fh, us* __restrict__ fl,
                                              us* __restrict__ gh, us* __restrict__ gl,
                                              us* __restrict__ hb, us* __restrict__ ob) {
    int i = blockIdx.x * 256 + threadIdx.x;
    if (i >= Cc * Cc) return;
    float v = fw[i]; us hi = f2bf(v); fh[i] = hi; fl[i] = f2bf(v - bf2f(hi));
    v = gw[i]; hi = f2bf(v); gh[i] = hi; gl[i] = f2bf(v - bf2f(hi));
    hb[i] = f2h(hw[i]);
    ob[i] = f2h(ow[i]);
}

// ------------- MFMA GEMM: C[m][n'] = sum_k A[m][k]*B[n'][k] -------------
// A m-major (lda), B n'-major (ldb). BMxBN tile, BK per barrier pair
// (BK/32 sub-tiles [row][32]), 4 waves (2x2), frags 16x16x32.
// SPLIT (bf16 only): hi/lo planes, acc = Ah*Bh + Ah*Bl + Al*Bh.
// F16: inputs are fp16, single plane, mfma_f32_16x16x32_f16.
// EPI: 0 fp32 store, 1 fp16 store.  BIAS: 0 none, 1 bias[row], 2 bias[col].
// SWZ: chunked XCD swizzle of the linearized block id (requires nwg % 8 == 0).
// KSPLIT > 1: blockIdx.z selects a K-chunk (K/KSPLIT); out slab per split via
//   strideC (pass strideA=strideB=0, EPI=0, no bias/resid). Deterministic.
template <bool SPLIT, int EPI, int BIAS, bool RESID, int BM, int BN, int BK, bool SWZ, bool F16, int KSPLIT>
__global__ __launch_bounds__(256) void mfma_gemm(
    const us* __restrict__ Ahi, const us* __restrict__ Alo, int lda, long long strideA,
    const us* __restrict__ Bhi, const us* __restrict__ Blo, int ldb, long long strideB,
    void* __restrict__ out0, int ldc, long long strideC,
    const float* __restrict__ bias, const float* __restrict__ resid, long long strideR,
    int K) {
    constexpr int WM = BM / 2, WN = BN / 2;
    constexpr int MI = WM / 16, NI = WN / 16;
    constexpr int AE = BM * BK, BE = BN * BK;   // elems per staged tile
    constexpr int ACH = AE / 512, BCH = BE / 512;
    __shared__ us smem[SPLIT ? 2 * (AE + BE) : (AE + BE)];
    us* As_hi = smem;
    us* Bs_hi = smem + AE;
    us* As_lo = nullptr;
    us* Bs_lo = nullptr;
    if constexpr (SPLIT) { As_lo = smem + AE + BE; Bs_lo = As_lo + AE; }

    int bz = blockIdx.z;
    const us* Ah = Ahi + (size_t)bz * strideA;
    const us* Bh = Bhi + (size_t)bz * strideB;
    const us* Al = nullptr;
    const us* Bl = nullptr;
    if constexpr (SPLIT) { Al = Alo + (size_t)bz * strideA; Bl = Blo + (size_t)bz * strideB; }

    int bx = blockIdx.x, by = blockIdx.y;
    if constexpr (SWZ) {
        int nwg = gridDim.x * gridDim.y;          // must be % 8 == 0
        int bid = blockIdx.x + gridDim.x * blockIdx.y;
        int cpx = nwg >> 3;
        int swz = (bid & 7) * cpx + (bid >> 3);
        bx = swz % gridDim.x;
        by = swz / gridDim.x;
    }
    int m0 = by * BM, n0 = bx * BN;
    int tid = threadIdx.x, wave = tid >> 6, lane = tid & 63;
    int wr = wave >> 1, wc = wave & 1;
    int lr = lane & 15, lg = lane >> 4;

    int kbeg = 0, kend = K;
    if constexpr (KSPLIT > 1) {
        int kch = K / KSPLIT;
        kbeg = bz * kch;
        kend = kbeg + kch;
    }

    f32x4 acc[MI][NI];
#pragma unroll
    for (int i = 0; i < MI; ++i)
#pragma unroll
        for (int j = 0; j < NI; ++j) acc[i][j] = (f32x4){0.f, 0.f, 0.f, 0.f};

    for (int k0 = kbeg; k0 < kend; k0 += BK) {
        __syncthreads();
        // stage: 1KB chunks; sub-tile kb is [rows][32] at base + kb*rows*32
#pragma unroll
        for (int ch = wave; ch < ACH; ch += 4) {
            int e0 = ch * 512 + lane * 8;
            int kb = e0 / (BM * 32);
            int rem = e0 - kb * (BM * 32);
            int rr = rem >> 5, cc = rem & 31;
            const size_t ga = (size_t)(m0 + rr) * lda + k0 + kb * 32 + cc;
            gload_lds16(Ah + ga, As_hi + ch * 512);
            if constexpr (SPLIT) gload_lds16(Al + ga, As_lo + ch * 512);
        }
#pragma unroll
        for (int ch = wave; ch < BCH; ch += 4) {
            int e0 = ch * 512 + lane * 8;
            int kb = e0 / (BN * 32);
            int rem = e0 - kb * (BN * 32);
            int rr = rem >> 5, cc = rem & 31;
            const size_t gb = (size_t)(n0 + rr) * ldb + k0 + kb * 32 + cc;
            gload_lds16(Bh + gb, Bs_hi + ch * 512);
            if constexpr (SPLIT) gload_lds16(Bl + gb, Bs_lo + ch * 512);
        }
        asm volatile("s_waitcnt vmcnt(0)" ::: "memory");
        __syncthreads();

#pragma unroll
        for (int kb = 0; kb < BK / 32; ++kb) {
            const us* Abase = As_hi + kb * BM * 32;
            const us* Bbase = Bs_hi + kb * BN * 32;
            if constexpr (F16) {
                f16x8 a[MI], b[NI];
#pragma unroll
                for (int x = 0; x < MI; ++x)
                    a[x] = *reinterpret_cast<const f16x8*>(&Abase[(wr * WM + x * 16 + lr) * 32 + lg * 8]);
#pragma unroll
                for (int x = 0; x < NI; ++x)
                    b[x] = *reinterpret_cast<const f16x8*>(&Bbase[(wc * WN + x * 16 + lr) * 32 + lg * 8]);
#pragma unroll
                for (int mi = 0; mi < MI; ++mi)
#pragma unroll
                    for (int ni = 0; ni < NI; ++ni)
                        acc[mi][ni] = __builtin_amdgcn_mfma_f32_16x16x32_f16(a[mi], b[ni], acc[mi][ni], 0, 0, 0);
            } else if constexpr (SPLIT) {
                bf16x8 ah[MI], bh[NI], al[MI], bl[NI];
#pragma unroll
                for (int x = 0; x < MI; ++x) {
                    ah[x] = *reinterpret_cast<const bf16x8*>(&Abase[(wr * WM + x * 16 + lr) * 32 + lg * 8]);
                    al[x] = *reinterpret_cast<const bf16x8*>(&As_lo[kb * BM * 32 + (wr * WM + x * 16 + lr) * 32 + lg * 8]);
                }
#pragma unroll
                for (int x = 0; x < NI; ++x) {
                    bh[x] = *reinterpret_cast<const bf16x8*>(&Bbase[(wc * WN + x * 16 + lr) * 32 + lg * 8]);
                    bl[x] = *reinterpret_cast<const bf16x8*>(&Bs_lo[kb * BN * 32 + (wc * WN + x * 16 + lr) * 32 + lg * 8]);
                }
#pragma unroll
                for (int mi = 0; mi < MI; ++mi)
#pragma unroll
                    for (int ni = 0; ni < NI; ++ni) {
                        acc[mi][ni] = __builtin_amdgcn_mfma_f32_16x16x32_bf16(ah[mi], bh[ni], acc[mi][ni], 0, 0, 0);
                        acc[mi][ni] = __builtin_amdgcn_mfma_f32_16x16x32_bf16(ah[mi], bl[ni], acc[mi][ni], 0, 0, 0);
                        acc[mi][ni] = __builtin_amdgcn_mfma_f32_16x16x32_bf16(al[mi], bh[ni], acc[mi][ni], 0, 0, 0);
                    }
            } else {
                bf16x8 ah[MI], bh[NI];
#pragma unroll
                for (int x = 0; x < MI; ++x)
                    ah[x] = *reinterpret_cast<const bf16x8*>(&Abase[(wr * WM + x * 16 + lr) * 32 + lg * 8]);
#pragma unroll
                for (int x = 0; x < NI; ++x)
                    bh[x] = *reinterpret_cast<const bf16x8*>(&Bbase[(wc * WN + x * 16 + lr) * 32 + lg * 8]);
#pragma unroll
                for (int mi = 0; mi < MI; ++mi)
#pragma unroll
                    for (int ni = 0; ni < NI; ++ni)
                        acc[mi][ni] = __builtin_amdgcn_mfma_f32_16x16x32_bf16(ah[mi], bh[ni], acc[mi][ni], 0, 0, 0);
            }
        }
    }
    // epilogue: frag D element (lg*4+r, lr)
#pragma unroll
    for (int mi = 0; mi < MI; ++mi) {
        int row = m0 + wr * WM + mi * 16 + lg * 4;
#pragma unroll
        for (int ni = 0; ni < NI; ++ni) {
            int col = n0 + wc * WN + ni * 16 + lr;
#pragma unroll
            for (int r = 0; r < 4; ++r) {
                float v = acc[mi][ni][r];
                if constexpr (BIAS == 1) v += bias[row + r];
                if constexpr (BIAS == 2) v += bias[col];
                if constexpr (RESID)
                    v += resid[(size_t)bz * strideR + (size_t)(row + r) * ldc + col];
                size_t off = (size_t)bz * strideC + (size_t)(row + r) * ldc + col;
                if constexpr (EPI == 0) {
                    ((float*)out0)[off] = v;
                } else {
                    ((us*)out0)[off] = f2h(v);
                }
            }
        }
    }
}

// ------- reduce 4 fp32 partial slabs -> fp16 (PV split-K second stage) -------
__global__ __launch_bounds__(256) void reduce4_kernel(const float* __restrict__ part,
                                                      us* __restrict__ outh) {
    constexpr size_t SLAB = (size_t)Nn * Cc;   // 2M elems
    size_t i = ((size_t)blockIdx.x * 256 + threadIdx.x) * 4;
    float4 a = *reinterpret_cast<const float4*>(part + i);
    float4 b = *reinterpret_cast<const float4*>(part + SLAB + i);
    float4 c = *reinterpret_cast<const float4*>(part + 2 * SLAB + i);
    float4 d = *reinterpret_cast<const float4*>(part + 3 * SLAB + i);
    float x0 = a.x + b.x + c.x + d.x;
    float x1 = a.y + b.y + c.y + d.y;
    float x2 = a.z + b.z + c.z + d.z;
    float x3 = a.w + b.w + c.w + d.w;
    unsigned long long pk = (unsigned long long)f2h(x0)
        | ((unsigned long long)f2h(x1) << 16)
        | ((unsigned long long)f2h(x2) << 32)
        | ((unsigned long long)f2h(x3) << 48);
    *reinterpret_cast<unsigned long long*>(outh + i) = pk;
}

// ------------- row softmax fp32 -> normalized P fp16 -------------
__global__ __launch_bounds__(256) void softmax_kernel(const float* __restrict__ S,
                                                      us* __restrict__ P) {
    int row = blockIdx.x;
    const float4* r4 = reinterpret_cast<const float4*>(S + (size_t)row * Nn);
    int t = threadIdx.x;
    float4 v[4];
    float mx = -1e30f;
#pragma unroll
    for (int j = 0; j < 4; ++j) {
        v[j] = r4[t + 256 * j];
        mx = fmaxf(mx, fmaxf(fmaxf(v[j].x, v[j].y), fmaxf(v[j].z, v[j].w)));
    }
    for (int off = 32; off; off >>= 1) mx = fmaxf(mx, __shfl_down(mx, off));
    __shared__ float redm[4], reds[4];
    int wid = t >> 6;
    if ((t & 63) == 0) redm[wid] = mx;
    __syncthreads();
    mx = fmaxf(fmaxf(redm[0], redm[1]), fmaxf(redm[2], redm[3]));
    float s = 0.f;
#pragma unroll
    for (int j = 0; j < 4; ++j) {
        v[j].x = __expf(v[j].x - mx); v[j].y = __expf(v[j].y - mx);
        v[j].z = __expf(v[j].z - mx); v[j].w = __expf(v[j].w - mx);
        s += v[j].x + v[j].y + v[j].z + v[j].w;
    }
    for (int off = 32; off; off >>= 1) s += __shfl_down(s, off);
    if ((t & 63) == 0) reds[wid] = s;
    __syncthreads();
    s = reds[0] + reds[1] + reds[2] + reds[3];
    float inv = 1.f / s;
    unsigned long long* P8 = reinterpret_cast<unsigned long long*>(P + (size_t)row * Nn);
#pragma unroll
    for (int j = 0; j < 4; ++j) {
        unsigned long long pk = (unsigned long long)f2h(v[j].x * inv)
            | ((unsigned long long)f2h(v[j].y * inv) << 16)
            | ((unsigned long long)f2h(v[j].z * inv) << 32)
            | ((unsigned long long)f2h(v[j].w * inv) << 48);
        P8[t + 256 * j] = pk;
    }
}

extern "C" void kernel_launch(void* const* d_in, const int* in_sizes, int n_in,
                              void* d_out, int out_size, void* d_ws, size_t ws_size,
                              hipStream_t stream) {
    const float* content = (const float*)d_in[0];
    const float* style   = (const float*)d_in[1];
    const float* f_w = (const float*)d_in[2];
    const float* f_b = (const float*)d_in[3];
    const float* g_w = (const float*)d_in[4];
    const float* g_b = (const float*)d_in[5];
    const float* h_w = (const float*)d_in[6];
    const float* h_b = (const float*)d_in[7];
    const float* o_w = (const float*)d_in[8];
    const float* o_b = (const float*)d_in[9];
    float* out = (float*)d_out;
    char* ws = (char*)d_ws;

    const size_t PB  = (size_t)Cc * Nn;        // 2,097,152 elems per batch-plane
    const size_t TEN = PB * Bb;                // 8,388,608 elems (16 MB as 16-bit)

    // region A [0,80MB): packed inputs; first 64MB reused as S fp32 (per batch),
    //   then first 32MB reused as PV split-K partials (after softmax consumed S)
    us* CNhi = (us*)ws;
    us* CNlo = CNhi + TEN;
    us* SNhi = CNlo + TEN;
    us* SNlo = SNhi + TEN;
    us* SR   = SNlo + TEN;                     // style raw, fp16
    float* S_buf = (float*)ws;                 // 64MB overlay (CN+SN dead by then)
    float* partial = (float*)ws;               // 32MB overlay (S dead after softmax)
    // region B [80,144MB): conv outputs (fp16)
    us* FT  = SR + TEN;                        // F^T [q][c]
    us* GT  = FT + TEN;                        // G^T [s][c]
    us* Hbf = GT + TEN;                        // H   [c'][s]
    us* OT  = Hbf + TEN;                       // O^T [q][c']
    // region C: packed weights + stats + P (per-batch, 32MB fp16)
    us* fwh = OT + TEN;
    us* fwl = fwh + Cc * Cc;
    us* gwh = fwl + Cc * Cc;
    us* gwl = gwh + Cc * Cc;
    us* hwb = gwl + Cc * Cc;
    us* owb = hwb + Cc * Cc;
    float* meanC = (float*)(owb + Cc * Cc);
    float* rstdC = meanC + Bb * Cc;
    float* meanS = rstdC + Bb * Cc;
    float* rstdS = meanS + Bb * Cc;
    us* P = (us*)(rstdS + Bb * Cc);

    stats_kernel<<<Bb * Cc, 256, 0, stream>>>(content, meanC, rstdC);
    stats_kernel<<<Bb * Cc, 256, 0, stream>>>(style, meanS, rstdS);

    dim3 pgrid(Nn / 64, Cc / 64, Bb);
    pack_T<0><<<pgrid, 256, 0, stream>>>(content, meanC, rstdC, CNhi, CNlo);
    pack_T<0><<<pgrid, 256, 0, stream>>>(style, meanS, rstdS, SNhi, SNlo);
    pack_T<1><<<pgrid, 256, 0, stream>>>(style, nullptr, nullptr, SR, nullptr);
    pack_w<<<(Cc * Cc + 255) / 256, 256, 0, stream>>>(f_w, g_w, h_w, o_w,
                                                      fwh, fwl, gwh, gwl, hwb, owb);

    // F^T[q][c'] = sum_c CN[q][c] f_w[c'][c] + f_b[c']  (M=4096,N=512,K=512) split-bf16 -> fp16
    mfma_gemm<true, 1, 2, false, 128, 128, 32, false, false, 1><<<dim3(4, 32, Bb), 256, 0, stream>>>(
        CNhi, CNlo, Cc, (long long)PB, fwh, fwl, Cc, 0,
        FT, Cc, (long long)PB, f_b, nullptr, 0, Cc);
    // G^T likewise
    mfma_gemm<true, 1, 2, false, 128, 128, 32, false, false, 1><<<dim3(4, 32, Bb), 256, 0, stream>>>(
        SNhi, SNlo, Cc, (long long)PB, gwh, gwl, Cc, 0,
        GT, Cc, (long long)PB, g_b, nullptr, 0, Cc);
    // H[c'][s] = sum_c h_w[c'][c] SR[s][c] + h_b[c']   (M=512,N=4096,K=512) fp16
    mfma_gemm<false, 1, 1, false, 128, 128, 64, false, true, 1><<<dim3(32, 4, Bb), 256, 0, stream>>>(
        hwb, nullptr, Cc, 0, SR, nullptr, Cc, (long long)PB,
        Hbf, Nn, (long long)PB, h_b, nullptr, 0, Cc);

    for (int b = 0; b < Bb; ++b) {
        const size_t tb = (size_t)b * PB;
        // S[q][s] = sum_c F^T[q][c] G^T[s][c]  (M=N=4096,K=512) fp16 single pass
        mfma_gemm<false, 0, 0, false, 128, 128, 64, true, true, 1><<<dim3(32, 32, 1), 256, 0, stream>>>(
            FT + tb, nullptr, Cc, 0, GT + tb, nullptr, Cc, 0,
            S_buf, Nn, 0, nullptr, nullptr, 0, Cc);
        softmax_kernel<<<Nn, 256, 0, stream>>>(S_buf, P);
        // O^T[q][c'] = sum_s P[q][s] H[c'][s]  (M=4096,N=512,K=4096) fp16
        // split-K=4 for occupancy (2048 blocks), fp32 partials into dead S region
        mfma_gemm<false, 0, 0, false, 64, 64, 64, true, true, 4><<<dim3(Cc / 64, Nn / 64, 4), 256, 0, stream>>>(
            P, nullptr, Nn, 0, Hbf + tb, nullptr, Nn, 0,
            partial, Cc, (long long)PB, nullptr, nullptr, 0, Nn);
        reduce4_kernel<<<(int)(PB / 4 / 256), 256, 0, stream>>>(partial, OT + tb);
    }

    // out[c'][n] = sum_c o_w[c'][c] O^T[n][c] + o_b[c'] + content[c'][n]  fp16 in, fp32 out
    mfma_gemm<false, 0, 1, true, 128, 128, 64, false, true, 1><<<dim3(32, 4, Bb), 256, 0, stream>>>(
        owb, nullptr, Cc, 0, OT, nullptr, Cc, (long long)PB,
        out, Nn, (long long)PB, o_b, content, (long long)PB, Cc);
}

// Round 9
// 445.212 us; speedup vs baseline: 26.5667x; 1.1019x over previous
//
#include <hip/hip_runtime.h>

constexpr int Cc = 512;
constexpr int Nn = 4096;   // 64*64
constexpr int Bb = 4;
#define EPS 1e-5f

using f16x8 = __attribute__((ext_vector_type(8))) _Float16;
using f32x4 = __attribute__((ext_vector_type(4))) float;
typedef unsigned short us;

__device__ __forceinline__ us f2h(float f) {
    union { _Float16 h; us u; } v; v.h = (_Float16)f;
    return v.u;
}
__device__ __forceinline__ void gload_lds16(const void* g, void* l) {
    __builtin_amdgcn_global_load_lds(
        (const __attribute__((address_space(1))) void*)g,
        (__attribute__((address_space(3))) void*)l, 16, 0, 0);
}

// ---------------- stats: per (b,c) mean & rstd (unbiased var) ----------------
__global__ __launch_bounds__(256) void stats_kernel(const float* __restrict__ x,
                                                    float* __restrict__ mean,
                                                    float* __restrict__ rstd) {
    int bc = blockIdx.x;
    const float* row = x + (size_t)bc * Nn;
    float s = 0.f, sq = 0.f;
    for (int i = threadIdx.x * 4; i < Nn; i += 256 * 4) {
        float4 v = *reinterpret_cast<const float4*>(row + i);
        s  += v.x + v.y + v.z + v.w;
        sq += v.x*v.x + v.y*v.y + v.z*v.z + v.w*v.w;
    }
    for (int off = 32; off; off >>= 1) {
        s  += __shfl_down(s, off);
        sq += __shfl_down(sq, off);
    }
    __shared__ float ls[4], lsq[4];
    int wid = threadIdx.x >> 6;
    if ((threadIdx.x & 63) == 0) { ls[wid] = s; lsq[wid] = sq; }
    __syncthreads();
    if (threadIdx.x == 0) {
        float S  = ls[0] + ls[1] + ls[2] + ls[3];
        float SQ = lsq[0] + lsq[1] + lsq[2] + lsq[3];
        float m  = S / (float)Nn;
        float var = (SQ - S * m) / (float)(Nn - 1);
        mean[bc] = m;
        rstd[bc] = rsqrtf(var + EPS);
    }
}

// ------ pack fp32 [b][c][n] -> fp16 transposed [b][n][c], optional inst-norm ------
template <bool NORM>
__global__ __launch_bounds__(256) void pack_T(const float* __restrict__ X,
                                              const float* __restrict__ mean,
                                              const float* __restrict__ rstd,
                                              us* __restrict__ T0) {
    int b = blockIdx.z;
    int n0 = blockIdx.x * 64, c0 = blockIdx.y * 64;
    __shared__ float tile[64][65];
    const float* Xb = X + (size_t)b * Cc * Nn;
    for (int i = threadIdx.x; i < 64 * 64; i += 256) {
        int c = i >> 6, n = i & 63;
        float v = Xb[(size_t)(c0 + c) * Nn + n0 + n];
        if constexpr (NORM) {
            int cg = b * Cc + c0 + c;
            v = (v - mean[cg]) * rstd[cg];
        }
        tile[c][n] = v;
    }
    __syncthreads();
    us* Pb = T0 + (size_t)b * Nn * Cc;
    for (int i = threadIdx.x; i < 64 * 64; i += 256) {
        int n = i >> 6, c = i & 63;
        Pb[(size_t)(n0 + n) * Cc + c0 + c] = f2h(tile[c][n]);
    }
}

// ------ pack the four 512x512 weights to fp16 ------
__global__ __launch_bounds__(256) void pack_w(const float* __restrict__ fw, const float* __restrict__ gw,
                                              const float* __restrict__ hw, const float* __restrict__ ow,
                                              us* __restrict__ fo, us* __restrict__ go,
                                              us* __restrict__ ho, us* __restrict__ oo) {
    int i = blockIdx.x * 256 + threadIdx.x;
    if (i >= Cc * Cc) return;
    fo[i] = f2h(fw[i]);
    go[i] = f2h(gw[i]);
    ho[i] = f2h(hw[i]);
    oo[i] = f2h(ow[i]);
}

// ------------- fp16 MFMA GEMM: C[m][n'] = sum_k A[m][k]*B[n'][k] -------------
// A m-major (lda), B n'-major (ldb). BMxBN tile, BK per barrier pair
// (BK/32 sub-tiles [rows][32]), 4 waves (2x2), frags mfma_f32_16x16x32_f16.
// EPI: 0 fp32 store, 1 fp16 store.  BIAS: 0 none, 1 bias[row], 2 bias[col].
// SWZ: chunked XCD swizzle of linearized block id (requires nwg % 8 == 0).
// KSPLIT > 1: blockIdx.z = K-chunk; out slab per split via strideC
//   (strideA=strideB=0, EPI=0, no bias/resid). Deterministic.
template <int EPI, int BIAS, bool RESID, int BM, int BN, int BK, bool SWZ, int KSPLIT>
__global__ __launch_bounds__(256) void mfma_gemm(
    const us* __restrict__ A, int lda, long long strideA,
    const us* __restrict__ B, int ldb, long long strideB,
    void* __restrict__ out0, int ldc, long long strideC,
    const float* __restrict__ bias, const float* __restrict__ resid, long long strideR,
    int K) {
    constexpr int WM = BM / 2, WN = BN / 2;
    constexpr int MI = WM / 16, NI = WN / 16;
    constexpr int AE = BM * BK, BE = BN * BK;
    constexpr int ACH = AE / 512, BCH = BE / 512;
    __shared__ us smem[AE + BE];
    us* As = smem;
    us* Bs = smem + AE;

    int bz = blockIdx.z;
    const us* Ab = A + (size_t)bz * strideA;
    const us* Bbp = B + (size_t)bz * strideB;

    int bx = blockIdx.x, by = blockIdx.y;
    if constexpr (SWZ) {
        int nwg = gridDim.x * gridDim.y;          // must be % 8 == 0
        int bid = blockIdx.x + gridDim.x * blockIdx.y;
        int cpx = nwg >> 3;
        int swz = (bid & 7) * cpx + (bid >> 3);
        bx = swz % gridDim.x;
        by = swz / gridDim.x;
    }
    int m0 = by * BM, n0 = bx * BN;
    int tid = threadIdx.x, wave = tid >> 6, lane = tid & 63;
    int wr = wave >> 1, wc = wave & 1;
    int lr = lane & 15, lg = lane >> 4;

    int kbeg = 0, kend = K;
    if constexpr (KSPLIT > 1) {
        int kch = K / KSPLIT;
        kbeg = bz * kch;
        kend = kbeg + kch;
    }

    f32x4 acc[MI][NI];
#pragma unroll
    for (int i = 0; i < MI; ++i)
#pragma unroll
        for (int j = 0; j < NI; ++j) acc[i][j] = (f32x4){0.f, 0.f, 0.f, 0.f};

    for (int k0 = kbeg; k0 < kend; k0 += BK) {
        __syncthreads();
        // stage: 1KB chunks; sub-tile kb is [rows][32] at base + kb*rows*32
#pragma unroll
        for (int ch = wave; ch < ACH; ch += 4) {
            int e0 = ch * 512 + lane * 8;
            int kb = e0 / (BM * 32);
            int rem = e0 - kb * (BM * 32);
            int rr = rem >> 5, cc = rem & 31;
            gload_lds16(Ab + (size_t)(m0 + rr) * lda + k0 + kb * 32 + cc, As + ch * 512);
        }
#pragma unroll
        for (int ch = wave; ch < BCH; ch += 4) {
            int e0 = ch * 512 + lane * 8;
            int kb = e0 / (BN * 32);
            int rem = e0 - kb * (BN * 32);
            int rr = rem >> 5, cc = rem & 31;
            gload_lds16(Bbp + (size_t)(n0 + rr) * ldb + k0 + kb * 32 + cc, Bs + ch * 512);
        }
        asm volatile("s_waitcnt vmcnt(0)" ::: "memory");
        __syncthreads();

#pragma unroll
        for (int kb = 0; kb < BK / 32; ++kb) {
            const us* Abase = As + kb * BM * 32;
            const us* Bbase = Bs + kb * BN * 32;
            f16x8 a[MI], b[NI];
#pragma unroll
            for (int x = 0; x < MI; ++x)
                a[x] = *reinterpret_cast<const f16x8*>(&Abase[(wr * WM + x * 16 + lr) * 32 + lg * 8]);
#pragma unroll
            for (int x = 0; x < NI; ++x)
                b[x] = *reinterpret_cast<const f16x8*>(&Bbase[(wc * WN + x * 16 + lr) * 32 + lg * 8]);
#pragma unroll
            for (int mi = 0; mi < MI; ++mi)
#pragma unroll
                for (int ni = 0; ni < NI; ++ni)
                    acc[mi][ni] = __builtin_amdgcn_mfma_f32_16x16x32_f16(a[mi], b[ni], acc[mi][ni], 0, 0, 0);
        }
    }
    // epilogue: frag D element (lg*4+r, lr)
#pragma unroll
    for (int mi = 0; mi < MI; ++mi) {
        int row = m0 + wr * WM + mi * 16 + lg * 4;
#pragma unroll
        for (int ni = 0; ni < NI; ++ni) {
            int col = n0 + wc * WN + ni * 16 + lr;
#pragma unroll
            for (int r = 0; r < 4; ++r) {
                float v = acc[mi][ni][r];
                if constexpr (BIAS == 1) v += bias[row + r];
                if constexpr (BIAS == 2) v += bias[col];
                if constexpr (RESID)
                    v += resid[(size_t)bz * strideR + (size_t)(row + r) * ldc + col];
                size_t off = (size_t)bz * strideC + (size_t)(row + r) * ldc + col;
                if constexpr (EPI == 0) {
                    ((float*)out0)[off] = v;
                } else {
                    ((us*)out0)[off] = f2h(v);
                }
            }
        }
    }
}

// ------- reduce 4 fp32 partial slabs -> fp16 (PV split-K second stage) -------
__global__ __launch_bounds__(256) void reduce4_kernel(const float* __restrict__ part,
                                                      us* __restrict__ outh) {
    constexpr size_t SLAB = (size_t)Nn * Cc;   // 2M elems
    size_t i = ((size_t)blockIdx.x * 256 + threadIdx.x) * 4;
    float4 a = *reinterpret_cast<const float4*>(part + i);
    float4 b = *reinterpret_cast<const float4*>(part + SLAB + i);
    float4 c = *reinterpret_cast<const float4*>(part + 2 * SLAB + i);
    float4 d = *reinterpret_cast<const float4*>(part + 3 * SLAB + i);
    float x0 = a.x + b.x + c.x + d.x;
    float x1 = a.y + b.y + c.y + d.y;
    float x2 = a.z + b.z + c.z + d.z;
    float x3 = a.w + b.w + c.w + d.w;
    unsigned long long pk = (unsigned long long)f2h(x0)
        | ((unsigned long long)f2h(x1) << 16)
        | ((unsigned long long)f2h(x2) << 32)
        | ((unsigned long long)f2h(x3) << 48);
    *reinterpret_cast<unsigned long long*>(outh + i) = pk;
}

// ------------- row softmax fp16 -> normalized P fp16 -------------
__global__ __launch_bounds__(256) void softmax_kernel(const us* __restrict__ S,
                                                      us* __restrict__ P) {
    int row = blockIdx.x;
    const f16x8* r8 = reinterpret_cast<const f16x8*>(S + (size_t)row * Nn);
    int t = threadIdx.x;
    float f[16];
    float mx = -1e30f;
#pragma unroll
    for (int j = 0; j < 2; ++j) {
        f16x8 v = r8[t + 256 * j];
#pragma unroll
        for (int e = 0; e < 8; ++e) {
            f[j * 8 + e] = (float)v[e];
            mx = fmaxf(mx, f[j * 8 + e]);
        }
    }
    for (int off = 32; off; off >>= 1) mx = fmaxf(mx, __shfl_down(mx, off));
    __shared__ float redm[4], reds[4];
    int wid = t >> 6;
    if ((t & 63) == 0) redm[wid] = mx;
    __syncthreads();
    mx = fmaxf(fmaxf(redm[0], redm[1]), fmaxf(redm[2], redm[3]));
    float s = 0.f;
#pragma unroll
    for (int j = 0; j < 16; ++j) {
        f[j] = __expf(f[j] - mx);
        s += f[j];
    }
    for (int off = 32; off; off >>= 1) s += __shfl_down(s, off);
    if ((t & 63) == 0) reds[wid] = s;
    __syncthreads();
    s = reds[0] + reds[1] + reds[2] + reds[3];
    float inv = 1.f / s;
    f16x8* P8 = reinterpret_cast<f16x8*>(P + (size_t)row * Nn);
#pragma unroll
    for (int j = 0; j < 2; ++j) {
        f16x8 o;
#pragma unroll
        for (int e = 0; e < 8; ++e) o[e] = (_Float16)(f[j * 8 + e] * inv);
        P8[t + 256 * j] = o;
    }
}

extern "C" void kernel_launch(void* const* d_in, const int* in_sizes, int n_in,
                              void* d_out, int out_size, void* d_ws, size_t ws_size,
                              hipStream_t stream) {
    const float* content = (const float*)d_in[0];
    const float* style   = (const float*)d_in[1];
    const float* f_w = (const float*)d_in[2];
    const float* f_b = (const float*)d_in[3];
    const float* g_w = (const float*)d_in[4];
    const float* g_b = (const float*)d_in[5];
    const float* h_w = (const float*)d_in[6];
    const float* h_b = (const float*)d_in[7];
    const float* o_w = (const float*)d_in[8];
    const float* o_b = (const float*)d_in[9];
    float* out = (float*)d_out;
    char* ws = (char*)d_ws;

    const size_t PB   = (size_t)Cc * Nn;       // 2,097,152 elems per batch-plane
    const size_t TEN  = PB * Bb;               // 8,388,608 elems (16 MB as fp16)
    const size_t SMAT = (size_t)Nn * Nn;       // 16,777,216 elems (32 MB as fp16)

    // [0,48MB): packed inputs fp16: CN, SN, SR. S fp16 (32MB) overlays CN+SN
    //   (both dead once F/G convs finish; SR stays live for H conv).
    us* CN = (us*)ws;
    us* SN = CN + TEN;
    us* SR = SN + TEN;
    us* S_buf = (us*)ws;                       // 32MB overlay of CN+SN
    // [48,112MB): conv outputs fp16
    us* FT  = SR + TEN;                        // F^T [q][c]
    us* GT  = FT + TEN;                        // G^T [s][c]
    us* Hbf = GT + TEN;                        // H   [c'][s]
    us* OT  = Hbf + TEN;                       // O^T [q][c']
    // [112MB,...): weights fp16, stats, P fp16 (32MB), partial fp32 (32MB)
    us* fwh = OT + TEN;
    us* gwh = fwh + Cc * Cc;
    us* hwb = gwh + Cc * Cc;
    us* owb = hwb + Cc * Cc;
    float* meanC = (float*)(owb + Cc * Cc);
    float* rstdC = meanC + Bb * Cc;
    float* meanS = rstdC + Bb * Cc;
    float* rstdS = meanS + Bb * Cc;
    us* P = (us*)(rstdS + Bb * Cc);
    float* partial = (float*)(P + SMAT);       // AFTER the full 32MB P buffer

    stats_kernel<<<Bb * Cc, 256, 0, stream>>>(content, meanC, rstdC);
    stats_kernel<<<Bb * Cc, 256, 0, stream>>>(style, meanS, rstdS);

    dim3 pgrid(Nn / 64, Cc / 64, Bb);
    pack_T<true><<<pgrid, 256, 0, stream>>>(content, meanC, rstdC, CN);
    pack_T<true><<<pgrid, 256, 0, stream>>>(style, meanS, rstdS, SN);
    pack_T<false><<<pgrid, 256, 0, stream>>>(style, nullptr, nullptr, SR);
    pack_w<<<(Cc * Cc + 255) / 256, 256, 0, stream>>>(f_w, g_w, h_w, o_w,
                                                      fwh, gwh, hwb, owb);

    // F^T[q][c'] = sum_c CN[q][c] f_w[c'][c] + f_b[c']  (M=4096,N=512,K=512)
    mfma_gemm<1, 2, false, 64, 64, 64, true, 1><<<dim3(Cc / 64, Nn / 64, Bb), 256, 0, stream>>>(
        CN, Cc, (long long)PB, fwh, Cc, 0,
        FT, Cc, (long long)PB, f_b, nullptr, 0, Cc);
    // G^T likewise
    mfma_gemm<1, 2, false, 64, 64, 64, true, 1><<<dim3(Cc / 64, Nn / 64, Bb), 256, 0, stream>>>(
        SN, Cc, (long long)PB, gwh, Cc, 0,
        GT, Cc, (long long)PB, g_b, nullptr, 0, Cc);
    // H[c'][s] = sum_c h_w[c'][c] SR[s][c] + h_b[c']   (M=512,N=4096,K=512)
    mfma_gemm<1, 1, false, 64, 64, 64, true, 1><<<dim3(Nn / 64, Cc / 64, Bb), 256, 0, stream>>>(
        hwb, Cc, 0, SR, Cc, (long long)PB,
        Hbf, Nn, (long long)PB, h_b, nullptr, 0, Cc);

    for (int b = 0; b < Bb; ++b) {
        const size_t tb = (size_t)b * PB;
        // S[q][s] = sum_c F^T[q][c] G^T[s][c]  (M=N=4096,K=512), fp16 out
        mfma_gemm<1, 0, false, 128, 128, 64, true, 1><<<dim3(32, 32, 1), 256, 0, stream>>>(
            FT + tb, Cc, 0, GT + tb, Cc, 0,
            S_buf, Nn, 0, nullptr, nullptr, 0, Cc);
        softmax_kernel<<<Nn, 256, 0, stream>>>(S_buf, P);
        // O^T[q][c'] = sum_s P[q][s] H[c'][s]  (M=4096,N=512,K=4096)
        // split-K=4 (2048 blocks), fp32 partial slabs, deterministic reduce
        mfma_gemm<0, 0, false, 64, 64, 64, true, 4><<<dim3(Cc / 64, Nn / 64, 4), 256, 0, stream>>>(
            P, Nn, 0, Hbf + tb, Nn, 0,
            partial, Cc, (long long)PB, nullptr, nullptr, 0, Nn);
        reduce4_kernel<<<(int)(PB / 4 / 256), 256, 0, stream>>>(partial, OT + tb);
    }

    // out[c'][n] = sum_c o_w[c'][c] O^T[n][c] + o_b[c'] + content[c'][n]
    mfma_gemm<0, 1, true, 64, 64, 64, true, 1><<<dim3(Nn / 64, Cc / 64, Bb), 256, 0, stream>>>(
        owb, Cc, 0, OT, Cc, (long long)PB,
        out, Nn, (long long)PB, o_b, content, (long long)PB, Cc);
}

// Round 10
// 443.332 us; speedup vs baseline: 26.6794x; 1.0042x over previous
//
#include <hip/hip_runtime.h>

constexpr int Cc = 512;
constexpr int Nn = 4096;   // 64*64
constexpr int Bb = 4;
#define EPS 1e-5f

using f16x8 = __attribute__((ext_vector_type(8))) _Float16;
using f32x4 = __attribute__((ext_vector_type(4))) float;
typedef unsigned short us;

__device__ __forceinline__ us f2h(float f) {
    union { _Float16 h; us u; } v; v.h = (_Float16)f;
    return v.u;
}
__device__ __forceinline__ void gload_lds16(const void* g, void* l) {
    __builtin_amdgcn_global_load_lds(
        (const __attribute__((address_space(1))) void*)g,
        (__attribute__((address_space(3))) void*)l, 16, 0, 0);
}

// ---------------- stats: per (b,c) mean & rstd (unbiased var) ----------------
__global__ __launch_bounds__(256) void stats_kernel(const float* __restrict__ x,
                                                    float* __restrict__ mean,
                                                    float* __restrict__ rstd) {
    int bc = blockIdx.x;
    const float* row = x + (size_t)bc * Nn;
    float s = 0.f, sq = 0.f;
    for (int i = threadIdx.x * 4; i < Nn; i += 256 * 4) {
        float4 v = *reinterpret_cast<const float4*>(row + i);
        s  += v.x + v.y + v.z + v.w;
        sq += v.x*v.x + v.y*v.y + v.z*v.z + v.w*v.w;
    }
    for (int off = 32; off; off >>= 1) {
        s  += __shfl_down(s, off);
        sq += __shfl_down(sq, off);
    }
    __shared__ float ls[4], lsq[4];
    int wid = threadIdx.x >> 6;
    if ((threadIdx.x & 63) == 0) { ls[wid] = s; lsq[wid] = sq; }
    __syncthreads();
    if (threadIdx.x == 0) {
        float S  = ls[0] + ls[1] + ls[2] + ls[3];
        float SQ = lsq[0] + lsq[1] + lsq[2] + lsq[3];
        float m  = S / (float)Nn;
        float var = (SQ - S * m) / (float)(Nn - 1);
        mean[bc] = m;
        rstd[bc] = rsqrtf(var + EPS);
    }
}

// ------ pack fp32 [b][c][n] -> fp16 transposed [b][n][c], optional inst-norm ------
template <bool NORM>
__global__ __launch_bounds__(256) void pack_T(const float* __restrict__ X,
                                              const float* __restrict__ mean,
                                              const float* __restrict__ rstd,
                                              us* __restrict__ T0) {
    int b = blockIdx.z;
    int n0 = blockIdx.x * 64, c0 = blockIdx.y * 64;
    __shared__ float tile[64][65];
    const float* Xb = X + (size_t)b * Cc * Nn;
    for (int i = threadIdx.x; i < 64 * 64; i += 256) {
        int c = i >> 6, n = i & 63;
        float v = Xb[(size_t)(c0 + c) * Nn + n0 + n];
        if constexpr (NORM) {
            int cg = b * Cc + c0 + c;
            v = (v - mean[cg]) * rstd[cg];
        }
        tile[c][n] = v;
    }
    __syncthreads();
    us* Pb = T0 + (size_t)b * Nn * Cc;
    for (int i = threadIdx.x; i < 64 * 64; i += 256) {
        int n = i >> 6, c = i & 63;
        Pb[(size_t)(n0 + n) * Cc + c0 + c] = f2h(tile[c][n]);
    }
}

// ------ pack the four 512x512 weights to fp16 ------
__global__ __launch_bounds__(256) void pack_w(const float* __restrict__ fw, const float* __restrict__ gw,
                                              const float* __restrict__ hw, const float* __restrict__ ow,
                                              us* __restrict__ fo, us* __restrict__ go,
                                              us* __restrict__ ho, us* __restrict__ oo) {
    int i = blockIdx.x * 256 + threadIdx.x;
    if (i >= Cc * Cc) return;
    fo[i] = f2h(fw[i]);
    go[i] = f2h(gw[i]);
    ho[i] = f2h(hw[i]);
    oo[i] = f2h(ow[i]);
}

// ------------- fp16 MFMA GEMM: C[m][n'] = sum_k A[m][k]*B[n'][k] -------------
// A m-major (lda), B n'-major (ldb). BMxBN tile, BK per barrier pair
// (BK/32 sub-tiles [rows][32]), 4 waves (2x2), frags mfma_f32_16x16x32_f16.
// EPI: 0 fp32 store, 1 fp16 store.  BIAS: 0 none, 1 bias[row], 2 bias[col].
// SWZ: 0 none; 1 chunked XCD swizzle (nwg % 8 == 0);
//      2 region XCD swizzle: 4x2 partition of (gridDim.y, gridDim.x) into 8
//        rectangles, one per XCD (needs gridDim.y%4==0, gridDim.x%2==0).
//        Keeps each XCD's A+B panels inside its private 4MB L2.
// KSPLIT > 1: blockIdx.z = K-chunk; out slab per split via strideC
//   (strideA=strideB=0, EPI=0, no bias/resid). Deterministic.
template <int EPI, int BIAS, bool RESID, int BM, int BN, int BK, int SWZ, int KSPLIT>
__global__ __launch_bounds__(256) void mfma_gemm(
    const us* __restrict__ A, int lda, long long strideA,
    const us* __restrict__ B, int ldb, long long strideB,
    void* __restrict__ out0, int ldc, long long strideC,
    const float* __restrict__ bias, const float* __restrict__ resid, long long strideR,
    int K) {
    constexpr int WM = BM / 2, WN = BN / 2;
    constexpr int MI = WM / 16, NI = WN / 16;
    constexpr int AE = BM * BK, BE = BN * BK;
    constexpr int ACH = AE / 512, BCH = BE / 512;
    __shared__ us smem[AE + BE];
    us* As = smem;
    us* Bs = smem + AE;

    int bz = blockIdx.z;
    const us* Ab = A + (size_t)bz * strideA;
    const us* Bbp = B + (size_t)bz * strideB;

    int bx = blockIdx.x, by = blockIdx.y;
    if constexpr (SWZ == 1) {
        int nwg = gridDim.x * gridDim.y;          // must be % 8 == 0
        int bid = blockIdx.x + gridDim.x * blockIdx.y;
        int cpx = nwg >> 3;
        int swz = (bid & 7) * cpx + (bid >> 3);
        bx = swz % gridDim.x;
        by = swz / gridDim.x;
    } else if constexpr (SWZ == 2) {
        int bid = blockIdx.x + gridDim.x * blockIdx.y;
        int xcd = bid & 7;
        int idx = bid >> 3;                       // [0, nwg/8)
        int rpr = gridDim.y >> 2;                 // rows per region
        int cpr = gridDim.x >> 1;                 // cols per region
        int row0 = (xcd >> 1) * rpr;
        int col0 = (xcd & 1) * cpr;
        by = row0 + idx / cpr;
        bx = col0 + idx % cpr;
    }
    int m0 = by * BM, n0 = bx * BN;
    int tid = threadIdx.x, wave = tid >> 6, lane = tid & 63;
    int wr = wave >> 1, wc = wave & 1;
    int lr = lane & 15, lg = lane >> 4;

    int kbeg = 0, kend = K;
    if constexpr (KSPLIT > 1) {
        int kch = K / KSPLIT;
        kbeg = bz * kch;
        kend = kbeg + kch;
    }

    f32x4 acc[MI][NI];
#pragma unroll
    for (int i = 0; i < MI; ++i)
#pragma unroll
        for (int j = 0; j < NI; ++j) acc[i][j] = (f32x4){0.f, 0.f, 0.f, 0.f};

    for (int k0 = kbeg; k0 < kend; k0 += BK) {
        __syncthreads();
        // stage: 1KB chunks; sub-tile kb is [rows][32] at base + kb*rows*32
#pragma unroll
        for (int ch = wave; ch < ACH; ch += 4) {
            int e0 = ch * 512 + lane * 8;
            int kb = e0 / (BM * 32);
            int rem = e0 - kb * (BM * 32);
            int rr = rem >> 5, cc = rem & 31;
            gload_lds16(Ab + (size_t)(m0 + rr) * lda + k0 + kb * 32 + cc, As + ch * 512);
        }
#pragma unroll
        for (int ch = wave; ch < BCH; ch += 4) {
            int e0 = ch * 512 + lane * 8;
            int kb = e0 / (BN * 32);
            int rem = e0 - kb * (BN * 32);
            int rr = rem >> 5, cc = rem & 31;
            gload_lds16(Bbp + (size_t)(n0 + rr) * ldb + k0 + kb * 32 + cc, Bs + ch * 512);
        }
        asm volatile("s_waitcnt vmcnt(0)" ::: "memory");
        __syncthreads();

#pragma unroll
        for (int kb = 0; kb < BK / 32; ++kb) {
            const us* Abase = As + kb * BM * 32;
            const us* Bbase = Bs + kb * BN * 32;
            f16x8 a[MI], b[NI];
#pragma unroll
            for (int x = 0; x < MI; ++x)
                a[x] = *reinterpret_cast<const f16x8*>(&Abase[(wr * WM + x * 16 + lr) * 32 + lg * 8]);
#pragma unroll
            for (int x = 0; x < NI; ++x)
                b[x] = *reinterpret_cast<const f16x8*>(&Bbase[(wc * WN + x * 16 + lr) * 32 + lg * 8]);
#pragma unroll
            for (int mi = 0; mi < MI; ++mi)
#pragma unroll
                for (int ni = 0; ni < NI; ++ni)
                    acc[mi][ni] = __builtin_amdgcn_mfma_f32_16x16x32_f16(a[mi], b[ni], acc[mi][ni], 0, 0, 0);
        }
    }
    // epilogue: frag D element (lg*4+r, lr)
#pragma unroll
    for (int mi = 0; mi < MI; ++mi) {
        int row = m0 + wr * WM + mi * 16 + lg * 4;
#pragma unroll
        for (int ni = 0; ni < NI; ++ni) {
            int col = n0 + wc * WN + ni * 16 + lr;
#pragma unroll
            for (int r = 0; r < 4; ++r) {
                float v = acc[mi][ni][r];
                if constexpr (BIAS == 1) v += bias[row + r];
                if constexpr (BIAS == 2) v += bias[col];
                if constexpr (RESID)
                    v += resid[(size_t)bz * strideR + (size_t)(row + r) * ldc + col];
                size_t off = (size_t)bz * strideC + (size_t)(row + r) * ldc + col;
                if constexpr (EPI == 0) {
                    ((float*)out0)[off] = v;
                } else {
                    ((us*)out0)[off] = f2h(v);
                }
            }
        }
    }
}

// ------- reduce 4 fp32 partial slabs -> fp16 (PV split-K second stage) -------
__global__ __launch_bounds__(256) void reduce4_kernel(const float* __restrict__ part,
                                                      us* __restrict__ outh) {
    constexpr size_t SLAB = (size_t)Nn * Cc;   // 2M elems
    size_t i = ((size_t)blockIdx.x * 256 + threadIdx.x) * 4;
    float4 a = *reinterpret_cast<const float4*>(part + i);
    float4 b = *reinterpret_cast<const float4*>(part + SLAB + i);
    float4 c = *reinterpret_cast<const float4*>(part + 2 * SLAB + i);
    float4 d = *reinterpret_cast<const float4*>(part + 3 * SLAB + i);
    float x0 = a.x + b.x + c.x + d.x;
    float x1 = a.y + b.y + c.y + d.y;
    float x2 = a.z + b.z + c.z + d.z;
    float x3 = a.w + b.w + c.w + d.w;
    unsigned long long pk = (unsigned long long)f2h(x0)
        | ((unsigned long long)f2h(x1) << 16)
        | ((unsigned long long)f2h(x2) << 32)
        | ((unsigned long long)f2h(x3) << 48);
    *reinterpret_cast<unsigned long long*>(outh + i) = pk;
}

// ------------- row softmax fp16 -> normalized P fp16 -------------
__global__ __launch_bounds__(256) void softmax_kernel(const us* __restrict__ S,
                                                      us* __restrict__ P) {
    int row = blockIdx.x;
    const f16x8* r8 = reinterpret_cast<const f16x8*>(S + (size_t)row * Nn);
    int t = threadIdx.x;
    float f[16];
    float mx = -1e30f;
#pragma unroll
    for (int j = 0; j < 2; ++j) {
        f16x8 v = r8[t + 256 * j];
#pragma unroll
        for (int e = 0; e < 8; ++e) {
            f[j * 8 + e] = (float)v[e];
            mx = fmaxf(mx, f[j * 8 + e]);
        }
    }
    for (int off = 32; off; off >>= 1) mx = fmaxf(mx, __shfl_down(mx, off));
    __shared__ float redm[4], reds[4];
    int wid = t >> 6;
    if ((t & 63) == 0) redm[wid] = mx;
    __syncthreads();
    mx = fmaxf(fmaxf(redm[0], redm[1]), fmaxf(redm[2], redm[3]));
    float s = 0.f;
#pragma unroll
    for (int j = 0; j < 16; ++j) {
        f[j] = __expf(f[j] - mx);
        s += f[j];
    }
    for (int off = 32; off; off >>= 1) s += __shfl_down(s, off);
    if ((t & 63) == 0) reds[wid] = s;
    __syncthreads();
    s = reds[0] + reds[1] + reds[2] + reds[3];
    float inv = 1.f / s;
    f16x8* P8 = reinterpret_cast<f16x8*>(P + (size_t)row * Nn);
#pragma unroll
    for (int j = 0; j < 2; ++j) {
        f16x8 o;
#pragma unroll
        for (int e = 0; e < 8; ++e) o[e] = (_Float16)(f[j * 8 + e] * inv);
        P8[t + 256 * j] = o;
    }
}

extern "C" void kernel_launch(void* const* d_in, const int* in_sizes, int n_in,
                              void* d_out, int out_size, void* d_ws, size_t ws_size,
                              hipStream_t stream) {
    const float* content = (const float*)d_in[0];
    const float* style   = (const float*)d_in[1];
    const float* f_w = (const float*)d_in[2];
    const float* f_b = (const float*)d_in[3];
    const float* g_w = (const float*)d_in[4];
    const float* g_b = (const float*)d_in[5];
    const float* h_w = (const float*)d_in[6];
    const float* h_b = (const float*)d_in[7];
    const float* o_w = (const float*)d_in[8];
    const float* o_b = (const float*)d_in[9];
    float* out = (float*)d_out;
    char* ws = (char*)d_ws;

    const size_t PB   = (size_t)Cc * Nn;       // 2,097,152 elems per batch-plane
    const size_t TEN  = PB * Bb;               // 8,388,608 elems (16 MB as fp16)
    const size_t SMAT = (size_t)Nn * Nn;       // 16,777,216 elems (32 MB as fp16)

    // [0,48MB): packed inputs fp16: CN, SN, SR. S fp16 (32MB) overlays CN+SN
    //   (both dead once F/G convs finish; SR stays live for H conv).
    us* CN = (us*)ws;
    us* SN = CN + TEN;
    us* SR = SN + TEN;
    us* S_buf = (us*)ws;                       // 32MB overlay of CN+SN
    // [48,112MB): conv outputs fp16
    us* FT  = SR + TEN;                        // F^T [q][c]
    us* GT  = FT + TEN;                        // G^T [s][c]
    us* Hbf = GT + TEN;                        // H   [c'][s]
    us* OT  = Hbf + TEN;                       // O^T [q][c']
    // [112MB,...): weights fp16, stats, P fp16 (32MB), partial fp32 (32MB)
    us* fwh = OT + TEN;
    us* gwh = fwh + Cc * Cc;
    us* hwb = gwh + Cc * Cc;
    us* owb = hwb + Cc * Cc;
    float* meanC = (float*)(owb + Cc * Cc);
    float* rstdC = meanC + Bb * Cc;
    float* meanS = rstdC + Bb * Cc;
    float* rstdS = meanS + Bb * Cc;
    us* P = (us*)(rstdS + Bb * Cc);
    float* partial = (float*)(P + SMAT);       // AFTER the full 32MB P buffer

    stats_kernel<<<Bb * Cc, 256, 0, stream>>>(content, meanC, rstdC);
    stats_kernel<<<Bb * Cc, 256, 0, stream>>>(style, meanS, rstdS);

    dim3 pgrid(Nn / 64, Cc / 64, Bb);
    pack_T<true><<<pgrid, 256, 0, stream>>>(content, meanC, rstdC, CN);
    pack_T<true><<<pgrid, 256, 0, stream>>>(style, meanS, rstdS, SN);
    pack_T<false><<<pgrid, 256, 0, stream>>>(style, nullptr, nullptr, SR);
    pack_w<<<(Cc * Cc + 255) / 256, 256, 0, stream>>>(f_w, g_w, h_w, o_w,
                                                      fwh, gwh, hwb, owb);

    // F^T[q][c'] = sum_c CN[q][c] f_w[c'][c] + f_b[c']  (M=4096,N=512,K=512)
    mfma_gemm<1, 2, false, 64, 64, 64, 1, 1><<<dim3(Cc / 64, Nn / 64, Bb), 256, 0, stream>>>(
        CN, Cc, (long long)PB, fwh, Cc, 0,
        FT, Cc, (long long)PB, f_b, nullptr, 0, Cc);
    // G^T likewise
    mfma_gemm<1, 2, false, 64, 64, 64, 1, 1><<<dim3(Cc / 64, Nn / 64, Bb), 256, 0, stream>>>(
        SN, Cc, (long long)PB, gwh, Cc, 0,
        GT, Cc, (long long)PB, g_b, nullptr, 0, Cc);
    // H[c'][s] = sum_c h_w[c'][c] SR[s][c] + h_b[c']   (M=512,N=4096,K=512)
    mfma_gemm<1, 1, false, 64, 64, 64, 1, 1><<<dim3(Nn / 64, Cc / 64, Bb), 256, 0, stream>>>(
        hwb, Cc, 0, SR, Cc, (long long)PB,
        Hbf, Nn, (long long)PB, h_b, nullptr, 0, Cc);

    for (int b = 0; b < Bb; ++b) {
        const size_t tb = (size_t)b * PB;
        // S[q][s] = sum_c F^T[q][c] G^T[s][c]  (M=N=4096,K=512), fp16 out
        // region (4x2) XCD swizzle: per-XCD panels A 1MB + B 2MB fit 4MB L2
        mfma_gemm<1, 0, false, 128, 128, 64, 2, 1><<<dim3(32, 32, 1), 256, 0, stream>>>(
            FT + tb, Cc, 0, GT + tb, Cc, 0,
            S_buf, Nn, 0, nullptr, nullptr, 0, Cc);
        softmax_kernel<<<Nn, 256, 0, stream>>>(S_buf, P);
        // O^T[q][c'] = sum_s P[q][s] H[c'][s]  (M=4096,N=512,K=4096)
        // split-K=4 (2048 blocks), fp32 partial slabs, deterministic reduce
        mfma_gemm<0, 0, false, 64, 64, 64, 1, 4><<<dim3(Cc / 64, Nn / 64, 4), 256, 0, stream>>>(
            P, Nn, 0, Hbf + tb, Nn, 0,
            partial, Cc, (long long)PB, nullptr, nullptr, 0, Nn);
        reduce4_kernel<<<(int)(PB / 4 / 256), 256, 0, stream>>>(partial, OT + tb);
    }

    // out[c'][n] = sum_c o_w[c'][c] O^T[n][c] + o_b[c'] + content[c'][n]
    mfma_gemm<0, 1, true, 64, 64, 64, 1, 1><<<dim3(Nn / 64, Cc / 64, Bb), 256, 0, stream>>>(
        owb, Cc, 0, OT, Cc, (long long)PB,
        out, Nn, (long long)PB, o_b, content, (long long)PB, Cc);
}